// Round 14
// baseline (368.868 us; speedup 1.0000x reference)
//
#include <hip/hip_runtime.h>
#include <hip/hip_bf16.h>
#include <math.h>

// Problem constants (match reference)
#define Bg 16
#define Nn 2048
#define Ee (1<<20)
#define NT (Bg*Nn)
#define INC 256
#define DIMd 128
#define OUTC 6
#define ENCH 100
#define NATOMS 20
#define BINCAP 3072   // per-bin edge capacity: mean 2048, sigma~44 -> +23 sigma

typedef __attribute__((ext_vector_type(8))) short bf16x8;
typedef __attribute__((ext_vector_type(4))) float f32x4;

__device__ __forceinline__ float gelu_f(float x){
    return 0.5f*x*(1.0f+erff(x*0.70710678118654752440f));
}
__device__ __forceinline__ unsigned short f2b(float f){
    __hip_bfloat16 h = __float2bfloat16(f);
    return *(unsigned short*)&h;
}
__device__ __forceinline__ float b2f(unsigned short u){
    unsigned v = ((unsigned)u)<<16;
    return __uint_as_float(v);
}
// split fp32 into bf16 hi + bf16 lo (v ~= hi + lo, dropped residual ~2^-18 rel)
__device__ __forceinline__ void splitf(float v, unsigned short& hi, unsigned short& lo){
    unsigned short h = f2b(v);
    hi = h; lo = f2b(v - b2f(h));
}
// async global->LDS, 16B per lane. LDS dest = per-lane ptr matching
// wave-uniform-base + lane*16 layout (m97 pattern).
__device__ __forceinline__ void gld16(const void* g, void* l){
    __builtin_amdgcn_global_load_lds(
        (const __attribute__((address_space(1))) unsigned*)g,
        (__attribute__((address_space(3))) unsigned*)l, 16, 0, 0);
}

// ---- Kernel 1: prep0 ------------------------------------------------------
// TAIL-FIRST block ordering (R11 showed a serial tail: scatter/wsplit blocks
// dispatched last ran at 0.75 blocks/CU after streaming finished -> 45 us).
//  blocks 0..255  : edge bucket-scatter, 4096 edges each (2x blocks of R11)
//  blocks 256..319: W2/Wm/A1 weight splits
//  blocks 320..831: BN stats + RAW x hi/lo split, 64 rows/block, float4 loads
__global__ __launch_bounds__(256) void prep0_k(const float* __restrict__ x,
    float* __restrict__ stats, const float* __restrict__ W2,
    const float* __restrict__ Wm, const float* __restrict__ A1,
    short* __restrict__ w2th, short* __restrict__ w2tl,
    short* __restrict__ wmth, short* __restrict__ wmtl,
    short* __restrict__ a1th, short* __restrict__ a1tl,
    unsigned short* __restrict__ xh, unsigned short* __restrict__ xl,
    const int* __restrict__ ei, unsigned* __restrict__ ecnt,
    unsigned* __restrict__ earena)
{
    __shared__ float sp1[4*256], sp2[4*256];     // 8 KB stats partials
    __shared__ unsigned scat[1024];
    int bx = blockIdx.x, tid = threadIdx.x;
    if(bx < 256){
        // ---- edge bucket-scatter (256 blocks; 4096 edges each) ------------
        unsigned* lcnt  = scat;              // 512 u32
        unsigned* gbase = scat + 512;
        for(int l=tid; l<512; l+=256) lcnt[l] = 0;
        __syncthreads();
        int ebase = bx * 4096;
        #pragma unroll 8
        for(int i=0;i<16;i++){
            int e = ebase + i*256 + tid;
            int s = ei[e], d = ei[Ee+e];
            if((s>>11)==(d>>11)) atomicAdd(&lcnt[s>>6], 1u);
        }
        __syncthreads();
        for(int l=tid; l<512; l+=256){
            unsigned c = lcnt[l];
            gbase[l] = c ? atomicAdd(&ecnt[l], c) : 0u;
            lcnt[l] = 0;
        }
        __syncthreads();
        #pragma unroll 8
        for(int i=0;i<16;i++){
            int e = ebase + i*256 + tid;
            int s = ei[e], d = ei[Ee+e];
            if((s>>11)==(d>>11)){
                int bin = s>>6;
                unsigned r = atomicAdd(&lcnt[bin], 1u);
                unsigned pos = gbase[bin] + r;
                if(pos < BINCAP)
                    earena[(size_t)bin*BINCAP + pos] =
                        ((unsigned)(s&63)<<11) | (unsigned)(d&2047);
            }
        }
    } else if(bx < 320){
        int gid = (bx-256)*256 + tid;             // 64 blocks -> 16384 threads
        unsigned short hi, lo;
        for(int l=gid;l<32768;l+=16384){ int n=l>>8,k=l&255;
            splitf(W2[(size_t)k*128+n],hi,lo); w2th[l]=(short)hi; w2tl[l]=(short)lo; }
        for(int l=gid;l<16384;l+=16384){ int n=l>>7,k=l&127;
            splitf(Wm[(size_t)k*128+n],hi,lo); wmth[l]=(short)hi; wmtl[l]=(short)lo; }
        for(int l=gid;l<16384;l+=16384){ int n=l>>7,k=l&127;
            float v=(n<ENCH)? A1[(size_t)k*ENCH+n] : 0.f;
            splitf(v,hi,lo); a1th[l]=(short)hi; a1tl[l]=(short)lo; }
    } else {
        int cg = (tid&63)*4;                     // 4-col group
        int rr = tid>>6;                         // row phase 0..3
        int r0 = (bx-320)*64;
        float s0=0,s1=0,s2=0,s3=0, q0=0,q1=0,q2=0,q3=0;
        #pragma unroll
        for(int i=0;i<16;i++){
            int r = r0 + rr + i*4;
            size_t off = (size_t)r*INC + cg;
            float4 v = *(const float4*)&x[off];
            ushort4 hi, lo;
            splitf(v.x,hi.x,lo.x); splitf(v.y,hi.y,lo.y);
            splitf(v.z,hi.z,lo.z); splitf(v.w,hi.w,lo.w);
            *(ushort4*)&xh[off] = hi;
            *(ushort4*)&xl[off] = lo;
            s0+=v.x; s1+=v.y; s2+=v.z; s3+=v.w;
            q0+=v.x*v.x; q1+=v.y*v.y; q2+=v.z*v.z; q3+=v.w*v.w;
        }
        sp1[rr*256+cg]=s0; sp1[rr*256+cg+1]=s1;
        sp1[rr*256+cg+2]=s2; sp1[rr*256+cg+3]=s3;
        sp2[rr*256+cg]=q0; sp2[rr*256+cg+1]=q1;
        sp2[rr*256+cg+2]=q2; sp2[rr*256+cg+3]=q3;
        __syncthreads();
        {
            float a = sp1[tid]+sp1[256+tid]+sp1[512+tid]+sp1[768+tid];
            float b = sp2[tid]+sp2[256+tid]+sp2[512+tid]+sp2[768+tid];
            atomicAdd(&stats[tid], a);
            atomicAdd(&stats[INC+tid], b);
        }
    }
}

// ---- Kernel 1c: prep1 = BN fold. W1' = s*W1 -> hi/lo planes (blocks 0..63);
//                 b1' = b1 + t@W1 (block 64). Runs after stats complete.
__global__ __launch_bounds__(256) void prep1_k(const float* __restrict__ stats,
    const float* __restrict__ gamma, const float* __restrict__ beta,
    const float* __restrict__ W1, const float* __restrict__ b1,
    short* __restrict__ w1th, short* __restrict__ w1tl, float* __restrict__ b1p)
{
    __shared__ float sc[256], sh[256];
    int bx = blockIdx.x, tid = threadIdx.x;
    {
        float mu  = stats[tid]*(1.0f/NT);
        float var = stats[256+tid]*(1.0f/NT) - mu*mu;
        float s = gamma[tid]/sqrtf(var + 1e-5f);
        sc[tid] = s; sh[tid] = beta[tid] - mu*s;
    }
    __syncthreads();
    if(bx < 64){
        int gid = bx*256 + tid;
        unsigned short hi, lo;
        for(int l=gid;l<65536;l+=16384){ int n=l>>8,k=l&255;
            splitf(sc[k]*W1[(size_t)k*256+n],hi,lo);
            w1th[l]=(short)hi; w1tl[l]=(short)lo; }
    } else {
        float acc = b1[tid];
        for(int k=0;k<256;k++) acc += sh[k]*W1[(size_t)k*256+tid];
        b1p[tid] = acc;
    }
}

// ---- Kernel 2: h1 = gelu(x@W1'+b1'), 64x256 tile, 3-term split MFMA -------
// Staging via global_load_lds width=16 (no VGPR round-trip). Unpadded LDS
// [rows][32] per plane; per-lane global src; lds dest = tid*16B (m97 layout).
// A = raw-x planes, read in-place and overwritten with h1 in the epilogue
// (legal: each block owns rows [64b,64b+64) exclusively).
__global__ __launch_bounds__(256) void gemm1_k(
    unsigned short* xh, unsigned short* xl,
    const short* __restrict__ w1th, const short* __restrict__ w1tl,
    const float* __restrict__ b1p)
{
    __shared__ __align__(16) short sAh[64*32], sAl[64*32];     // 4 KB each
    __shared__ __align__(16) short sBh[256*32], sBl[256*32];   // 16 KB each
    int tid = threadIdx.x;
    int row0 = blockIdx.x*64;
    int lane = tid&63, w = tid>>6;
    int ln = lane&15, quad = lane>>4;
    int m0w = (w&1)*32, n0b = (w>>1)*128;
    int ar = tid>>2, kc = (tid&3)*8;             // staging coords
    f32x4 acc[2][8];
    #pragma unroll
    for(int i=0;i<2;i++)
        #pragma unroll
        for(int j=0;j<8;j++) acc[i][j] = (f32x4){0.f,0.f,0.f,0.f};

    for(int k0=0;k0<256;k0+=32){
        // A: 64 rows x 32 k, 1 issue per plane
        gld16(xh + (size_t)(row0+ar)*256 + k0 + kc, &sAh[tid*8]);
        gld16(xl + (size_t)(row0+ar)*256 + k0 + kc, &sAl[tid*8]);
        // B: 256 rows x 32 k, 4 issues per plane
        #pragma unroll
        for(int i=0;i<4;i++){
            size_t go = (size_t)(i*64+ar)*256 + k0 + kc;
            gld16(w1th + go, &sBh[i*2048 + tid*8]);
            gld16(w1tl + go, &sBl[i*2048 + tid*8]);
        }
        __syncthreads();                 // vmcnt(0) drain -> tiles ready
        bf16x8 ah[2], al[2];
        #pragma unroll
        for(int tm=0;tm<2;tm++){
            ah[tm] = *(const bf16x8*)&sAh[(m0w+tm*16+ln)*32 + quad*8];
            al[tm] = *(const bf16x8*)&sAl[(m0w+tm*16+ln)*32 + quad*8];
        }
        #pragma unroll
        for(int tn=0;tn<8;tn++){
            bf16x8 bh = *(const bf16x8*)&sBh[(n0b+tn*16+ln)*32 + quad*8];
            bf16x8 bl = *(const bf16x8*)&sBl[(n0b+tn*16+ln)*32 + quad*8];
            #pragma unroll
            for(int tm=0;tm<2;tm++){
                acc[tm][tn] = __builtin_amdgcn_mfma_f32_16x16x32_bf16(al[tm], bh, acc[tm][tn], 0,0,0);
                acc[tm][tn] = __builtin_amdgcn_mfma_f32_16x16x32_bf16(ah[tm], bl, acc[tm][tn], 0,0,0);
                acc[tm][tn] = __builtin_amdgcn_mfma_f32_16x16x32_bf16(ah[tm], bh, acc[tm][tn], 0,0,0);
            }
        }
        __syncthreads();                 // LDS reads done before next stage
    }
    #pragma unroll
    for(int tn=0;tn<8;tn++){
        int col = n0b + tn*16 + ln;
        float bias = b1p[col];
        #pragma unroll
        for(int tm=0;tm<2;tm++){
            int rowb = row0 + m0w + tm*16 + quad*4;
            #pragma unroll
            for(int r=0;r<4;r++){
                float hv = gelu_f(acc[tm][tn][r] + bias);
                unsigned short hi, lo;
                splitf(hv, hi, lo);
                xh[(size_t)(rowb+r)*256 + col] = hi;     // h1 overwrites x
                xl[(size_t)(rowb+r)*256 + col] = lo;
            }
        }
    }
}

// ------ Kernel 3: h2=gelu(h1@W2+b2) via global_load_lds staging; -----------
// logits+argmax in-block. grid 512, 4 waves, wave=32m x 64n. h2s/w3s overlay
// the dead staging arena after the GEMM loop.
__global__ __launch_bounds__(256) void gemm23_mfma(
    const unsigned short* __restrict__ h1h, const unsigned short* __restrict__ h1l,
    const short* __restrict__ w2th, const short* __restrict__ w2tl,
    const float* __restrict__ b2, const float* __restrict__ W3,
    const float* __restrict__ b3, int* __restrict__ ids)
{
    __shared__ __align__(16) char arena[44032];
    short* sAh = (short*)arena;                 // 4096 B
    short* sAl = (short*)(arena + 4096);        // 4096 B
    short* sBh = (short*)(arena + 8192);        // 8192 B
    short* sBl = (short*)(arena + 16384);       // 8192 B
    float* h2s = (float*)arena;                 // 64*132 f32 = 33792 B
    float* w3s = (float*)(arena + 33792);       // 2560 f32 = 10240 B
    __shared__ float lgs[64*20];
    int tid = threadIdx.x;
    int row0 = blockIdx.x*64;
    int lane = tid&63, w = tid>>6;
    int ln = lane&15, quad = lane>>4;
    int m0w = (w&1)*32, n0w = (w>>1)*64;
    int ar = tid>>2, kc = (tid&3)*8;
    f32x4 acc[2][4];
    #pragma unroll
    for(int i=0;i<2;i++)
        #pragma unroll
        for(int j=0;j<4;j++) acc[i][j] = (f32x4){0.f,0.f,0.f,0.f};

    for(int k0=0;k0<256;k0+=32){
        gld16(h1h + (size_t)(row0+ar)*256 + k0 + kc, &sAh[tid*8]);
        gld16(h1l + (size_t)(row0+ar)*256 + k0 + kc, &sAl[tid*8]);
        #pragma unroll
        for(int i=0;i<2;i++){
            size_t go = (size_t)(i*64+ar)*256 + k0 + kc;
            gld16(w2th + go, &sBh[i*2048 + tid*8]);
            gld16(w2tl + go, &sBl[i*2048 + tid*8]);
        }
        __syncthreads();
        bf16x8 ah[2], al[2];
        #pragma unroll
        for(int tm=0;tm<2;tm++){
            ah[tm] = *(const bf16x8*)&sAh[(m0w+tm*16+ln)*32 + quad*8];
            al[tm] = *(const bf16x8*)&sAl[(m0w+tm*16+ln)*32 + quad*8];
        }
        #pragma unroll
        for(int tn=0;tn<4;tn++){
            bf16x8 bh = *(const bf16x8*)&sBh[(n0w+tn*16+ln)*32 + quad*8];
            bf16x8 bl = *(const bf16x8*)&sBl[(n0w+tn*16+ln)*32 + quad*8];
            #pragma unroll
            for(int tm=0;tm<2;tm++){
                acc[tm][tn] = __builtin_amdgcn_mfma_f32_16x16x32_bf16(al[tm], bh, acc[tm][tn], 0,0,0);
                acc[tm][tn] = __builtin_amdgcn_mfma_f32_16x16x32_bf16(ah[tm], bl, acc[tm][tn], 0,0,0);
                acc[tm][tn] = __builtin_amdgcn_mfma_f32_16x16x32_bf16(ah[tm], bh, acc[tm][tn], 0,0,0);
            }
        }
        __syncthreads();                 // staging arena dead after last iter
    }
    // epilogue: h2 -> overlaid LDS
    #pragma unroll
    for(int tn=0;tn<4;tn++){
        int col = n0w + tn*16 + ln;
        float bias = b2[col];
        #pragma unroll
        for(int tm=0;tm<2;tm++){
            int rb = m0w + tm*16 + quad*4;
            #pragma unroll
            for(int r=0;r<4;r++)
                h2s[(rb+r)*132 + col] = gelu_f(acc[tm][tn][r] + bias);
        }
    }
    for(int l=tid;l<2560;l+=256) w3s[l] = W3[l];
    __syncthreads();
    int n = tid>>2, q = tid&3;
    float lg[5] = {};
    #pragma unroll 4
    for(int k=0;k<128;k++){
        float h = h2s[n*132+k];
        #pragma unroll
        for(int a=0;a<5;a++) lg[a] += h*w3s[k*20 + q*5 + a];
    }
    #pragma unroll
    for(int a=0;a<5;a++) lgs[n*20 + q*5 + a] = lg[a] + b3[q*5+a];
    __syncthreads();
    if(tid<64){                                     // numpy argmax: first max wins
        float best = lgs[tid*20]; int bi = 0;
        #pragma unroll
        for(int a=1;a<20;a++){ float v2 = lgs[tid*20+a]; if(v2>best){best=v2;bi=a;} }
        ids[row0+tid] = bi;
    }
}

// ---- Kernel 4a: aggregation only -> v bf16 to workspace --------------------
// grid 512 bins x 256. LDS 33.8 KiB -> 4 blocks/CU. 3 barriers total.
__global__ __launch_bounds__(256) void msgA_k(
    const int* __restrict__ ids, const unsigned* __restrict__ ecnt,
    const unsigned* __restrict__ earena, const float* __restrict__ embed,
    unsigned short* __restrict__ vbf)
{
    __shared__ unsigned lmask[64*64];          // 16 KiB dst bitmask per node
    __shared__ unsigned ind[NATOMS*64];        // 5 KiB indicator bitmasks
    __shared__ unsigned char sid[2048];        // atom id per graph node
    __shared__ float emb[NATOMS*128];          // 10 KiB embedding table
    int tid = threadIdx.x;
    int bin = blockIdx.x;
    int row0 = bin*64;
    int g = bin>>5, tile = bin&31;
    int lane = tid&63, w = tid>>6;

    // --- phase 0 ------------------------------------------------------------
    for(int l=tid;l<NATOMS*128;l+=256) emb[l] = embed[l];
    #pragma unroll
    for(int i=0;i<8;i++){ int j = tid + i*256; sid[j] = (unsigned char)ids[g*Nn + j]; }
    #pragma unroll
    for(int i=0;i<16;i++) lmask[tid + i*256] = 0;
    int nb = min((int)ecnt[bin], BINCAP);
    __syncthreads();

    // --- phase 1: ballot indicator bitmasks + LDS adjacency build -----------
    for(int wp=w; wp<32; wp+=4){
        int a = sid[wp*64 + lane];
        #pragma unroll
        for(int atom=0; atom<NATOMS; atom++){
            unsigned long long bm = __ballot(a==atom);
            if(lane<2) ind[atom*64 + wp*2 + lane] = (unsigned)(bm >> (32*lane));
        }
    }
    for(int i=tid; i<nb; i+=256){
        unsigned wv = earena[(size_t)bin*BINCAP + i];
        int sl = wv>>11, dl = wv & 2047;
        atomicOr(&lmask[sl*64 + (dl>>5)], 1u<<(dl&31));
    }
    __syncthreads();

    // --- phase 2: per-node counts popcount(lmask & ind), 4-lane split -------
    int node = tid>>2, p = tid&3;
    unsigned mw[16];
    {
        const unsigned* mrow = &lmask[node*64 + p*16];
        *(uint4*)&mw[0]  = *(const uint4*)&mrow[0];
        *(uint4*)&mw[4]  = *(const uint4*)&mrow[4];
        *(uint4*)&mw[8]  = *(const uint4*)&mrow[8];
        *(uint4*)&mw[12] = *(const uint4*)&mrow[12];
    }
    int degi = 0;
    #pragma unroll
    for(int w2=0;w2<16;w2++) degi += __popc(mw[w2]);
    float cnt[NATOMS];
    #pragma unroll
    for(int a=0;a<NATOMS;a++){
        int c = 0;
        const unsigned* ia = &ind[a*64 + p*16];
        #pragma unroll
        for(int w2=0;w2<16;w2++) c += __popc(mw[w2] & ia[w2]);
        cnt[a] = (float)c;
    }
    #pragma unroll
    for(int a=0;a<NATOMS;a++){
        cnt[a] += __shfl_xor(cnt[a],1,64);
        cnt[a] += __shfl_xor(cnt[a],2,64);
    }
    float deg = (float)degi;
    deg += __shfl_xor(deg,1,64);
    deg += __shfl_xor(deg,2,64);

    // --- v = emb[own] + (sum_a cnt_a emb_a)/max(deg,1) -> global bf16 -------
    {
        float inv = 1.0f / fmaxf(deg, 1.0f);
        int oid = sid[tile*64 + node];
        int d0 = p*32;
        float vv[32];
        #pragma unroll
        for(int d=0;d<32;d++) vv[d]=0.f;
        #pragma unroll
        for(int a=0;a<NATOMS;a++){
            float ca = cnt[a];
            const float* ea = &emb[a*128 + d0];
            #pragma unroll
            for(int d=0;d<32;d+=4){
                float4 e = *(const float4*)&ea[d];
                vv[d]+=ca*e.x; vv[d+1]+=ca*e.y; vv[d+2]+=ca*e.z; vv[d+3]+=ca*e.w;
            }
        }
        const float* eo = &emb[oid*128 + d0];
        unsigned short* dst = vbf + (size_t)(row0+node)*128 + d0;
        #pragma unroll
        for(int d=0;d<32;d+=4){
            float4 e = *(const float4*)&eo[d];
            ushort4 o;
            o.x = f2b(e.x + vv[d]*inv);
            o.y = f2b(e.y + vv[d+1]*inv);
            o.z = f2b(e.z + vv[d+2]*inv);
            o.w = f2b(e.w + vv[d+3]*inv);
            *(ushort4*)&dst[d] = o;
        }
    }
}

// ---- Kernel 4b: hout GEMM + heads. MFMA operands DIRECT from global --------
// (A-frags from v bf16, B-frags from L2-resident transposed weight planes).
// No LDS staging for either GEMM -> no barriers inside the K loops.
// LDS ~22.5 KiB; __launch_bounds__(256,4) caps VGPR<=128 -> 4 blocks/CU.
__global__ __launch_bounds__(256,4) void msgB_k(
    const unsigned short* __restrict__ vbf,
    const short* __restrict__ wmth, const short* __restrict__ wmtl,
    const float* __restrict__ b_msg, const float* __restrict__ w_coor,
    const short* __restrict__ a1th, const short* __restrict__ a1tl,
    const float* __restrict__ a1v, const float* __restrict__ A2,
    const float* __restrict__ a2v, const float* __restrict__ dalpha,
    const float* __restrict__ dw, const float* __restrict__ db,
    const float* __restrict__ coords, float* __restrict__ out_ang,
    float* __restrict__ out_z, float* __restrict__ out_co)
{
    __shared__ unsigned short houts[64*136];   // hout bf16; later t1s [64][104]
    __shared__ float s_bm[128], s_wc[384], s_A2[624], s_a1[104];
    __shared__ float s_dyt[16], s_a2[8];
    int tid = threadIdx.x;
    int row0 = blockIdx.x*64;
    int lane = tid&63, w = tid>>6;
    int ln = lane&15, quad = lane>>4;
    int m0w = (w&1)*32, n0w = (w>>1)*64;

    // constants -> LDS (consumed only after the first barrier below)
    if(tid<128) s_bm[tid] = b_msg[tid];
    if(tid<104) s_a1[tid] = (tid<ENCH) ? a1v[tid] : 0.f;
    for(int l=tid;l<384;l+=256) s_wc[l] = w_coor[l];
    for(int l=tid;l<624;l+=256) s_A2[l] = (l<600) ? A2[l] : 0.f;
    if(tid==0)  s_dyt[0] = dalpha[0];
    if(tid<6){ s_dyt[1+tid] = dw[tid]; s_dyt[8+tid] = db[tid]; }
    if(tid<8)  s_a2[tid] = (tid<6) ? a2v[tid] : 0.f;

    // ---- hout = gelu(v @ W_msg + b), 2-term W split, operands from global --
    f32x4 acc[2][4];
    #pragma unroll
    for(int i=0;i<2;i++)
        #pragma unroll
        for(int j=0;j<4;j++) acc[i][j] = (f32x4){0.f,0.f,0.f,0.f};
    #pragma unroll
    for(int k0=0;k0<128;k0+=32){
        bf16x8 av[2];
        #pragma unroll
        for(int tm=0;tm<2;tm++)
            av[tm] = *(const bf16x8*)((const short*)vbf
                     + (size_t)(row0+m0w+tm*16+ln)*128 + k0 + quad*8);
        #pragma unroll
        for(int tn=0;tn<4;tn++){
            size_t bo = (size_t)(n0w+tn*16+ln)*128 + k0 + quad*8;
            bf16x8 bh = *(const bf16x8*)(wmth + bo);
            bf16x8 bl = *(const bf16x8*)(wmtl + bo);
            #pragma unroll
            for(int tm=0;tm<2;tm++){
                acc[tm][tn] = __builtin_amdgcn_mfma_f32_16x16x32_bf16(av[tm], bl, acc[tm][tn], 0,0,0);
                acc[tm][tn] = __builtin_amdgcn_mfma_f32_16x16x32_bf16(av[tm], bh, acc[tm][tn], 0,0,0);
            }
        }
    }
    __syncthreads();                    // constants staged
    // epilogue: z fp32 + hout bf16 to LDS
    #pragma unroll
    for(int tn=0;tn<4;tn++){
        int col = n0w + tn*16 + ln;
        float bias = s_bm[col];
        #pragma unroll
        for(int tm=0;tm<2;tm++){
            int mb2 = m0w + tm*16 + quad*4;
            #pragma unroll
            for(int r=0;r<4;r++){
                float hv = gelu_f(acc[tm][tn][r] + bias);
                out_z[(size_t)(row0+mb2+r)*128 + col] = hv;
                houts[(mb2+r)*136 + col] = f2b(hv);
            }
        }
    }
    __syncthreads();                    // houts ready

    int node = tid>>2, p = tid&3;
    // ---- coors: 4-lane k-split dot with w_coor -----------------------------
    {
        float d0=0.f, d1=0.f, d2=0.f;
        int kb = p*32;
        #pragma unroll
        for(int k=0;k<32;k+=4){
            ushort4 hv = *(const ushort4*)&houts[node*136 + kb + k];
            float h0=b2f(hv.x),h1=b2f(hv.y),h2=b2f(hv.z),h3=b2f(hv.w);
            const float* wc = &s_wc[(kb+k)*3];
            d0 += h0*wc[0]+h1*wc[3]+h2*wc[6]+h3*wc[9];
            d1 += h0*wc[1]+h1*wc[4]+h2*wc[7]+h3*wc[10];
            d2 += h0*wc[2]+h1*wc[5]+h2*wc[8]+h3*wc[11];
        }
        d0 += __shfl_xor(d0,1,64); d0 += __shfl_xor(d0,2,64);
        d1 += __shfl_xor(d1,1,64); d1 += __shfl_xor(d1,2,64);
        d2 += __shfl_xor(d2,1,64); d2 += __shfl_xor(d2,2,64);
        if(p==0){
            size_t o = (size_t)(row0+node)*3;
            out_co[o+0] = coords[o+0] + tanhf(d0);
            out_co[o+1] = coords[o+1] + tanhf(d1);
            out_co[o+2] = coords[o+2] + tanhf(d2);
        }
    }

    // ---- t1 = gelu(hout @ A1 + a1), 2-term split, B direct from global -----
    f32x4 acc2[2][4];
    #pragma unroll
    for(int i=0;i<2;i++)
        #pragma unroll
        for(int j=0;j<4;j++) acc2[i][j] = (f32x4){0.f,0.f,0.f,0.f};
    #pragma unroll
    for(int k0=0;k0<128;k0+=32){
        bf16x8 ah[2];
        #pragma unroll
        for(int tm=0;tm<2;tm++)
            ah[tm] = *(const bf16x8*)&houts[(m0w+tm*16+ln)*136 + k0 + quad*8];
        #pragma unroll
        for(int tn=0;tn<4;tn++){
            size_t bo = (size_t)(n0w+tn*16+ln)*128 + k0 + quad*8;
            bf16x8 bh = *(const bf16x8*)(a1th + bo);
            bf16x8 bl = *(const bf16x8*)(a1tl + bo);
            #pragma unroll
            for(int tm=0;tm<2;tm++){
                acc2[tm][tn] = __builtin_amdgcn_mfma_f32_16x16x32_bf16(ah[tm], bl, acc2[tm][tn], 0,0,0);
                acc2[tm][tn] = __builtin_amdgcn_mfma_f32_16x16x32_bf16(ah[tm], bh, acc2[tm][tn], 0,0,0);
            }
        }
    }
    __syncthreads();                    // houts reads done -> reuse as t1s
    unsigned short* t1s = houts;        // [64][104]
    #pragma unroll
    for(int tn=0;tn<4;tn++){
        int col = n0w + tn*16 + ln;
        if(col < 104){
            float bias = s_a1[col];
            #pragma unroll
            for(int tm=0;tm<2;tm++){
                int mb2 = m0w + tm*16 + quad*4;
                #pragma unroll
                for(int r=0;r<4;r++)
                    t1s[(mb2+r)*104 + col] = f2b(gelu_f(acc2[tm][tn][r] + bias));
            }
        }
    }
    __syncthreads();

    // ---- t2 = gelu(t1@A2+a2); DyT; angles ----------------------------------
    {
        int g0 = (p<2) ? p*7 : 14+(p-2)*6;
        int gcount = (p<2) ? 7 : 6;
        float s[6] = {0.f,0.f,0.f,0.f,0.f,0.f};
        for(int gg=0; gg<gcount; gg++){
            int kb = (g0+gg)*4;
            ushort4 tv = *(const ushort4*)&t1s[node*104 + kb];
            float u0=b2f(tv.x), u1=b2f(tv.y), u2=b2f(tv.z), u3=b2f(tv.w);
            #pragma unroll
            for(int j=0;j<6;j++)
                s[j] += u0*s_A2[kb*6+j] + u1*s_A2[(kb+1)*6+j]
                      + u2*s_A2[(kb+2)*6+j] + u3*s_A2[(kb+3)*6+j];
        }
        #pragma unroll
        for(int j=0;j<6;j++){ s[j]+=__shfl_xor(s[j],1,64); s[j]+=__shfl_xor(s[j],2,64); }
        if(p<2){
            size_t o = (size_t)(row0+node)*6 + p*3;
            #pragma unroll
            for(int jj=0;jj<3;jj++){
                int j = p*3+jj;
                float t2v = gelu_f(s[j] + s_a2[j]);
                float uu = tanhf(s_dyt[0]*t2v)*s_dyt[1+j] + s_dyt[8+j];
                out_ang[o+jj] = tanhf(uu);
            }
        }
    }
}

// ---------------------------------------------------------------------------
extern "C" void kernel_launch(void* const* d_in, const int* in_sizes, int n_in,
                              void* d_out, int out_size, void* d_ws, size_t ws_size,
                              hipStream_t stream) {
    const float* x      = (const float*)d_in[0];
    const float* coords = (const float*)d_in[1];
    const int*   ei     = (const int*)d_in[2];
    const float* gamma  = (const float*)d_in[4];
    const float* beta   = (const float*)d_in[5];
    const float* W1     = (const float*)d_in[6];
    const float* b1     = (const float*)d_in[7];
    const float* W2     = (const float*)d_in[8];
    const float* b2     = (const float*)d_in[9];
    const float* W3     = (const float*)d_in[10];
    const float* b3     = (const float*)d_in[11];
    const float* embed  = (const float*)d_in[12];
    const float* W_msg  = (const float*)d_in[13];
    const float* b_msg  = (const float*)d_in[14];
    const float* w_coor = (const float*)d_in[15];
    const float* A1     = (const float*)d_in[16];
    const float* a1v    = (const float*)d_in[17];
    const float* A2     = (const float*)d_in[18];
    const float* a2v    = (const float*)d_in[19];
    const float* dalpha = (const float*)d_in[20];
    const float* dw     = (const float*)d_in[21];
    const float* db     = (const float*)d_in[22];

    // ws layout (~44 MB peak):
    //  0      : ids   (128 KB)
    //  128K   : stats (2 KB) + ecnt (2 KB)   <- one 4 KB memset
    //  256K   : weight planes (512 KB) + b1p (1 KB)
    //  1M     : earena u32[512*3072] (6 MB)
    //  10M    : x-hi -> overwritten in-place by h1h -> reused as v bf16
    //  27M    : x-lo -> overwritten in-place by h1l
    char* ws = (char*)d_ws;
    int*      ids   = (int*)ws;
    float*    stats = (float*)(ws + 131072);
    unsigned* ecnt  = (unsigned*)(ws + 131072 + 2048);
    short*    w1th  = (short*)(ws + 262144);
    short*    w1tl  = w1th + 65536;
    short*    w2th  = w1tl + 65536;
    short*    w2tl  = w2th + 32768;
    short*    wmth  = w2tl + 32768;
    short*    wmtl  = wmth + 16384;
    short*    a1th  = wmtl + 16384;
    short*    a1tl  = a1th + 16384;
    float*    b1p   = (float*)(a1tl + 16384);
    unsigned* earena = (unsigned*)(ws + (1<<20));
    unsigned short* h1h = (unsigned short*)(ws + (size_t)10*1048576);
    unsigned short* h1l = (unsigned short*)(ws + (size_t)27*1048576);
    unsigned short* vbf = h1h;   // h1 planes dead after gemm23 -> reuse for v

    float* out_ang = (float*)d_out;
    float* out_z   = out_ang + (size_t)NT*OUTC;
    float* out_co  = out_z   + (size_t)NT*DIMd;

    hipMemsetAsync(stats, 0, 4096, stream);      // stats + ecnt
    prep0_k<<<832, 256, 0, stream>>>(x, stats, W2, W_msg, A1,
        w2th, w2tl, wmth, wmtl, a1th, a1tl, h1h, h1l, ei, ecnt, earena);
    prep1_k<<<65, 256, 0, stream>>>(stats, gamma, beta, W1, b1,
        w1th, w1tl, b1p);
    gemm1_k<<<512, 256, 0, stream>>>(h1h, h1l, w1th, w1tl, b1p);
    gemm23_mfma<<<512, 256, 0, stream>>>(h1h, h1l, w2th, w2tl, b2, W3, b3, ids);
    msgA_k<<<512, 256, 0, stream>>>(ids, ecnt, earena, embed, vbf);
    msgB_k<<<512, 256, 0, stream>>>(vbf, wmth, wmtl, b_msg, w_coor,
        a1th, a1tl, a1v, A2, a2v, dalpha, dw, db, coords,
        out_ang, out_z, out_co);
}

// Round 15
// 368.355 us; speedup vs baseline: 1.0014x; 1.0014x over previous
//
#include <hip/hip_runtime.h>
#include <hip/hip_bf16.h>
#include <math.h>

// Problem constants (match reference)
#define Bg 16
#define Nn 2048
#define Ee (1<<20)
#define NT (Bg*Nn)
#define INC 256
#define DIMd 128
#define OUTC 6
#define ENCH 100
#define NATOMS 20
#define BINCAP 3072   // per-bin edge capacity: mean 2048, sigma~44 -> +23 sigma

typedef __attribute__((ext_vector_type(8))) short bf16x8;
typedef __attribute__((ext_vector_type(4))) float f32x4;

__device__ __forceinline__ float gelu_f(float x){
    return 0.5f*x*(1.0f+erff(x*0.70710678118654752440f));
}
__device__ __forceinline__ unsigned short f2b(float f){
    __hip_bfloat16 h = __float2bfloat16(f);
    return *(unsigned short*)&h;
}
__device__ __forceinline__ float b2f(unsigned short u){
    unsigned v = ((unsigned)u)<<16;
    return __uint_as_float(v);
}
// split fp32 into bf16 hi + bf16 lo (v ~= hi + lo, dropped residual ~2^-18 rel)
__device__ __forceinline__ void splitf(float v, unsigned short& hi, unsigned short& lo){
    unsigned short h = f2b(v);
    hi = h; lo = f2b(v - b2f(h));
}
// async global->LDS, 16B per lane. LDS dest = per-lane ptr matching
// wave-uniform-base + lane*16 layout (m97 pattern).
__device__ __forceinline__ void gld16(const void* g, void* l){
    __builtin_amdgcn_global_load_lds(
        (const __attribute__((address_space(1))) unsigned*)g,
        (__attribute__((address_space(3))) unsigned*)l, 16, 0, 0);
}

// ---- Kernel 1: prep0 ------------------------------------------------------
// TAIL-FIRST block ordering (R11 showed a serial tail: scatter/wsplit blocks
// dispatched last ran at 0.75 blocks/CU after streaming finished -> 45 us).
//  blocks 0..255  : edge bucket-scatter, 4096 edges each (2x blocks of R11)
//  blocks 256..319: W2/Wm/A1 weight splits
//  blocks 320..831: BN stats + RAW x hi/lo split, 64 rows/block, float4 loads
__global__ __launch_bounds__(256) void prep0_k(const float* __restrict__ x,
    float* __restrict__ stats, const float* __restrict__ W2,
    const float* __restrict__ Wm, const float* __restrict__ A1,
    short* __restrict__ w2th, short* __restrict__ w2tl,
    short* __restrict__ wmth, short* __restrict__ wmtl,
    short* __restrict__ a1th, short* __restrict__ a1tl,
    unsigned short* __restrict__ xh, unsigned short* __restrict__ xl,
    const int* __restrict__ ei, unsigned* __restrict__ ecnt,
    unsigned* __restrict__ earena)
{
    __shared__ float sp1[4*256], sp2[4*256];     // 8 KB stats partials
    __shared__ unsigned scat[1024];
    int bx = blockIdx.x, tid = threadIdx.x;
    if(bx < 256){
        // ---- edge bucket-scatter (256 blocks; 4096 edges each) ------------
        unsigned* lcnt  = scat;              // 512 u32
        unsigned* gbase = scat + 512;
        for(int l=tid; l<512; l+=256) lcnt[l] = 0;
        __syncthreads();
        int ebase = bx * 4096;
        #pragma unroll 8
        for(int i=0;i<16;i++){
            int e = ebase + i*256 + tid;
            int s = ei[e], d = ei[Ee+e];
            if((s>>11)==(d>>11)) atomicAdd(&lcnt[s>>6], 1u);
        }
        __syncthreads();
        for(int l=tid; l<512; l+=256){
            unsigned c = lcnt[l];
            gbase[l] = c ? atomicAdd(&ecnt[l], c) : 0u;
            lcnt[l] = 0;
        }
        __syncthreads();
        #pragma unroll 8
        for(int i=0;i<16;i++){
            int e = ebase + i*256 + tid;
            int s = ei[e], d = ei[Ee+e];
            if((s>>11)==(d>>11)){
                int bin = s>>6;
                unsigned r = atomicAdd(&lcnt[bin], 1u);
                unsigned pos = gbase[bin] + r;
                if(pos < BINCAP)
                    earena[(size_t)bin*BINCAP + pos] =
                        ((unsigned)(s&63)<<11) | (unsigned)(d&2047);
            }
        }
    } else if(bx < 320){
        int gid = (bx-256)*256 + tid;             // 64 blocks -> 16384 threads
        unsigned short hi, lo;
        for(int l=gid;l<32768;l+=16384){ int n=l>>8,k=l&255;
            splitf(W2[(size_t)k*128+n],hi,lo); w2th[l]=(short)hi; w2tl[l]=(short)lo; }
        for(int l=gid;l<16384;l+=16384){ int n=l>>7,k=l&127;
            splitf(Wm[(size_t)k*128+n],hi,lo); wmth[l]=(short)hi; wmtl[l]=(short)lo; }
        for(int l=gid;l<16384;l+=16384){ int n=l>>7,k=l&127;
            float v=(n<ENCH)? A1[(size_t)k*ENCH+n] : 0.f;
            splitf(v,hi,lo); a1th[l]=(short)hi; a1tl[l]=(short)lo; }
    } else {
        int cg = (tid&63)*4;                     // 4-col group
        int rr = tid>>6;                         // row phase 0..3
        int r0 = (bx-320)*64;
        float s0=0,s1=0,s2=0,s3=0, q0=0,q1=0,q2=0,q3=0;
        #pragma unroll
        for(int i=0;i<16;i++){
            int r = r0 + rr + i*4;
            size_t off = (size_t)r*INC + cg;
            float4 v = *(const float4*)&x[off];
            ushort4 hi, lo;
            splitf(v.x,hi.x,lo.x); splitf(v.y,hi.y,lo.y);
            splitf(v.z,hi.z,lo.z); splitf(v.w,hi.w,lo.w);
            *(ushort4*)&xh[off] = hi;
            *(ushort4*)&xl[off] = lo;
            s0+=v.x; s1+=v.y; s2+=v.z; s3+=v.w;
            q0+=v.x*v.x; q1+=v.y*v.y; q2+=v.z*v.z; q3+=v.w*v.w;
        }
        sp1[rr*256+cg]=s0; sp1[rr*256+cg+1]=s1;
        sp1[rr*256+cg+2]=s2; sp1[rr*256+cg+3]=s3;
        sp2[rr*256+cg]=q0; sp2[rr*256+cg+1]=q1;
        sp2[rr*256+cg+2]=q2; sp2[rr*256+cg+3]=q3;
        __syncthreads();
        {
            float a = sp1[tid]+sp1[256+tid]+sp1[512+tid]+sp1[768+tid];
            float b = sp2[tid]+sp2[256+tid]+sp2[512+tid]+sp2[768+tid];
            atomicAdd(&stats[tid], a);
            atomicAdd(&stats[INC+tid], b);
        }
    }
}

// ---- Kernel 1c: prep1 = BN fold. W1' = s*W1 -> hi/lo planes (blocks 0..63);
//                 b1' = b1 + t@W1 (block 64). Runs after stats complete.
__global__ __launch_bounds__(256) void prep1_k(const float* __restrict__ stats,
    const float* __restrict__ gamma, const float* __restrict__ beta,
    const float* __restrict__ W1, const float* __restrict__ b1,
    short* __restrict__ w1th, short* __restrict__ w1tl, float* __restrict__ b1p)
{
    __shared__ float sc[256], sh[256];
    int bx = blockIdx.x, tid = threadIdx.x;
    {
        float mu  = stats[tid]*(1.0f/NT);
        float var = stats[256+tid]*(1.0f/NT) - mu*mu;
        float s = gamma[tid]/sqrtf(var + 1e-5f);
        sc[tid] = s; sh[tid] = beta[tid] - mu*s;
    }
    __syncthreads();
    if(bx < 64){
        int gid = bx*256 + tid;
        unsigned short hi, lo;
        for(int l=gid;l<65536;l+=16384){ int n=l>>8,k=l&255;
            splitf(sc[k]*W1[(size_t)k*256+n],hi,lo);
            w1th[l]=(short)hi; w1tl[l]=(short)lo; }
    } else {
        float acc = b1[tid];
        for(int k=0;k<256;k++) acc += sh[k]*W1[(size_t)k*256+tid];
        b1p[tid] = acc;
    }
}

// ---- Kernel 2: h1 = gelu(x@W1'+b1'), 64x256 tile, 3-term split MFMA -------
// Staging via global_load_lds width=16 (no VGPR round-trip). Unpadded LDS
// [rows][32] per plane; per-lane global src; lds dest = tid*16B (m97 layout).
// A = raw-x planes, read in-place and overwritten with h1 in the epilogue
// (legal: each block owns rows [64b,64b+64) exclusively).
__global__ __launch_bounds__(256) void gemm1_k(
    unsigned short* xh, unsigned short* xl,
    const short* __restrict__ w1th, const short* __restrict__ w1tl,
    const float* __restrict__ b1p)
{
    __shared__ __align__(16) short sAh[64*32], sAl[64*32];     // 4 KB each
    __shared__ __align__(16) short sBh[256*32], sBl[256*32];   // 16 KB each
    int tid = threadIdx.x;
    int row0 = blockIdx.x*64;
    int lane = tid&63, w = tid>>6;
    int ln = lane&15, quad = lane>>4;
    int m0w = (w&1)*32, n0b = (w>>1)*128;
    int ar = tid>>2, kc = (tid&3)*8;             // staging coords
    f32x4 acc[2][8];
    #pragma unroll
    for(int i=0;i<2;i++)
        #pragma unroll
        for(int j=0;j<8;j++) acc[i][j] = (f32x4){0.f,0.f,0.f,0.f};

    for(int k0=0;k0<256;k0+=32){
        // A: 64 rows x 32 k, 1 issue per plane
        gld16(xh + (size_t)(row0+ar)*256 + k0 + kc, &sAh[tid*8]);
        gld16(xl + (size_t)(row0+ar)*256 + k0 + kc, &sAl[tid*8]);
        // B: 256 rows x 32 k, 4 issues per plane
        #pragma unroll
        for(int i=0;i<4;i++){
            size_t go = (size_t)(i*64+ar)*256 + k0 + kc;
            gld16(w1th + go, &sBh[i*2048 + tid*8]);
            gld16(w1tl + go, &sBl[i*2048 + tid*8]);
        }
        __syncthreads();                 // vmcnt(0) drain -> tiles ready
        bf16x8 ah[2], al[2];
        #pragma unroll
        for(int tm=0;tm<2;tm++){
            ah[tm] = *(const bf16x8*)&sAh[(m0w+tm*16+ln)*32 + quad*8];
            al[tm] = *(const bf16x8*)&sAl[(m0w+tm*16+ln)*32 + quad*8];
        }
        #pragma unroll
        for(int tn=0;tn<8;tn++){
            bf16x8 bh = *(const bf16x8*)&sBh[(n0b+tn*16+ln)*32 + quad*8];
            bf16x8 bl = *(const bf16x8*)&sBl[(n0b+tn*16+ln)*32 + quad*8];
            #pragma unroll
            for(int tm=0;tm<2;tm++){
                acc[tm][tn] = __builtin_amdgcn_mfma_f32_16x16x32_bf16(al[tm], bh, acc[tm][tn], 0,0,0);
                acc[tm][tn] = __builtin_amdgcn_mfma_f32_16x16x32_bf16(ah[tm], bl, acc[tm][tn], 0,0,0);
                acc[tm][tn] = __builtin_amdgcn_mfma_f32_16x16x32_bf16(ah[tm], bh, acc[tm][tn], 0,0,0);
            }
        }
        __syncthreads();                 // LDS reads done before next stage
    }
    #pragma unroll
    for(int tn=0;tn<8;tn++){
        int col = n0b + tn*16 + ln;
        float bias = b1p[col];
        #pragma unroll
        for(int tm=0;tm<2;tm++){
            int rowb = row0 + m0w + tm*16 + quad*4;
            #pragma unroll
            for(int r=0;r<4;r++){
                float hv = gelu_f(acc[tm][tn][r] + bias);
                unsigned short hi, lo;
                splitf(hv, hi, lo);
                xh[(size_t)(rowb+r)*256 + col] = hi;     // h1 overwrites x
                xl[(size_t)(rowb+r)*256 + col] = lo;
            }
        }
    }
}

// ------ Kernel 3: h2=gelu(h1@W2+b2) via global_load_lds staging; -----------
// logits+argmax in-block. grid 512, 4 waves, wave=32m x 64n. h2s/w3s overlay
// the dead staging arena after the GEMM loop.
__global__ __launch_bounds__(256) void gemm23_mfma(
    const unsigned short* __restrict__ h1h, const unsigned short* __restrict__ h1l,
    const short* __restrict__ w2th, const short* __restrict__ w2tl,
    const float* __restrict__ b2, const float* __restrict__ W3,
    const float* __restrict__ b3, int* __restrict__ ids)
{
    __shared__ __align__(16) char arena[44032];
    short* sAh = (short*)arena;                 // 4096 B
    short* sAl = (short*)(arena + 4096);        // 4096 B
    short* sBh = (short*)(arena + 8192);        // 8192 B
    short* sBl = (short*)(arena + 16384);       // 8192 B
    float* h2s = (float*)arena;                 // 64*132 f32 = 33792 B
    float* w3s = (float*)(arena + 33792);       // 2560 f32 = 10240 B
    __shared__ float lgs[64*20];
    int tid = threadIdx.x;
    int row0 = blockIdx.x*64;
    int lane = tid&63, w = tid>>6;
    int ln = lane&15, quad = lane>>4;
    int m0w = (w&1)*32, n0w = (w>>1)*64;
    int ar = tid>>2, kc = (tid&3)*8;
    f32x4 acc[2][4];
    #pragma unroll
    for(int i=0;i<2;i++)
        #pragma unroll
        for(int j=0;j<4;j++) acc[i][j] = (f32x4){0.f,0.f,0.f,0.f};

    for(int k0=0;k0<256;k0+=32){
        gld16(h1h + (size_t)(row0+ar)*256 + k0 + kc, &sAh[tid*8]);
        gld16(h1l + (size_t)(row0+ar)*256 + k0 + kc, &sAl[tid*8]);
        #pragma unroll
        for(int i=0;i<2;i++){
            size_t go = (size_t)(i*64+ar)*256 + k0 + kc;
            gld16(w2th + go, &sBh[i*2048 + tid*8]);
            gld16(w2tl + go, &sBl[i*2048 + tid*8]);
        }
        __syncthreads();
        bf16x8 ah[2], al[2];
        #pragma unroll
        for(int tm=0;tm<2;tm++){
            ah[tm] = *(const bf16x8*)&sAh[(m0w+tm*16+ln)*32 + quad*8];
            al[tm] = *(const bf16x8*)&sAl[(m0w+tm*16+ln)*32 + quad*8];
        }
        #pragma unroll
        for(int tn=0;tn<4;tn++){
            bf16x8 bh = *(const bf16x8*)&sBh[(n0w+tn*16+ln)*32 + quad*8];
            bf16x8 bl = *(const bf16x8*)&sBl[(n0w+tn*16+ln)*32 + quad*8];
            #pragma unroll
            for(int tm=0;tm<2;tm++){
                acc[tm][tn] = __builtin_amdgcn_mfma_f32_16x16x32_bf16(al[tm], bh, acc[tm][tn], 0,0,0);
                acc[tm][tn] = __builtin_amdgcn_mfma_f32_16x16x32_bf16(ah[tm], bl, acc[tm][tn], 0,0,0);
                acc[tm][tn] = __builtin_amdgcn_mfma_f32_16x16x32_bf16(ah[tm], bh, acc[tm][tn], 0,0,0);
            }
        }
        __syncthreads();                 // staging arena dead after last iter
    }
    // epilogue: h2 -> overlaid LDS
    #pragma unroll
    for(int tn=0;tn<4;tn++){
        int col = n0w + tn*16 + ln;
        float bias = b2[col];
        #pragma unroll
        for(int tm=0;tm<2;tm++){
            int rb = m0w + tm*16 + quad*4;
            #pragma unroll
            for(int r=0;r<4;r++)
                h2s[(rb+r)*132 + col] = gelu_f(acc[tm][tn][r] + bias);
        }
    }
    for(int l=tid;l<2560;l+=256) w3s[l] = W3[l];
    __syncthreads();
    int n = tid>>2, q = tid&3;
    float lg[5] = {};
    #pragma unroll 4
    for(int k=0;k<128;k++){
        float h = h2s[n*132+k];
        #pragma unroll
        for(int a=0;a<5;a++) lg[a] += h*w3s[k*20 + q*5 + a];
    }
    #pragma unroll
    for(int a=0;a<5;a++) lgs[n*20 + q*5 + a] = lg[a] + b3[q*5+a];
    __syncthreads();
    if(tid<64){                                     // numpy argmax: first max wins
        float best = lgs[tid*20]; int bi = 0;
        #pragma unroll
        for(int a=1;a<20;a++){ float v2 = lgs[tid*20+a]; if(v2>best){best=v2;bi=a;} }
        ids[row0+tid] = bi;
    }
}

// ---- Kernel 4a: aggregation only -> v bf16 to workspace --------------------
// grid 512 bins x 256. LDS 33.8 KiB -> 4 blocks/CU. 3 barriers total.
__global__ __launch_bounds__(256) void msgA_k(
    const int* __restrict__ ids, const unsigned* __restrict__ ecnt,
    const unsigned* __restrict__ earena, const float* __restrict__ embed,
    unsigned short* __restrict__ vbf)
{
    __shared__ unsigned lmask[64*64];          // 16 KiB dst bitmask per node
    __shared__ unsigned ind[NATOMS*64];        // 5 KiB indicator bitmasks
    __shared__ unsigned char sid[2048];        // atom id per graph node
    __shared__ float emb[NATOMS*128];          // 10 KiB embedding table
    int tid = threadIdx.x;
    int bin = blockIdx.x;
    int row0 = bin*64;
    int g = bin>>5, tile = bin&31;
    int lane = tid&63, w = tid>>6;

    // --- phase 0 ------------------------------------------------------------
    for(int l=tid;l<NATOMS*128;l+=256) emb[l] = embed[l];
    #pragma unroll
    for(int i=0;i<8;i++){ int j = tid + i*256; sid[j] = (unsigned char)ids[g*Nn + j]; }
    #pragma unroll
    for(int i=0;i<16;i++) lmask[tid + i*256] = 0;
    int nb = min((int)ecnt[bin], BINCAP);
    __syncthreads();

    // --- phase 1: ballot indicator bitmasks + LDS adjacency build -----------
    for(int wp=w; wp<32; wp+=4){
        int a = sid[wp*64 + lane];
        #pragma unroll
        for(int atom=0; atom<NATOMS; atom++){
            unsigned long long bm = __ballot(a==atom);
            if(lane<2) ind[atom*64 + wp*2 + lane] = (unsigned)(bm >> (32*lane));
        }
    }
    for(int i=tid; i<nb; i+=256){
        unsigned wv = earena[(size_t)bin*BINCAP + i];
        int sl = wv>>11, dl = wv & 2047;
        atomicOr(&lmask[sl*64 + (dl>>5)], 1u<<(dl&31));
    }
    __syncthreads();

    // --- phase 2: per-node counts popcount(lmask & ind), 4-lane split -------
    int node = tid>>2, p = tid&3;
    unsigned mw[16];
    {
        const unsigned* mrow = &lmask[node*64 + p*16];
        *(uint4*)&mw[0]  = *(const uint4*)&mrow[0];
        *(uint4*)&mw[4]  = *(const uint4*)&mrow[4];
        *(uint4*)&mw[8]  = *(const uint4*)&mrow[8];
        *(uint4*)&mw[12] = *(const uint4*)&mrow[12];
    }
    int degi = 0;
    #pragma unroll
    for(int w2=0;w2<16;w2++) degi += __popc(mw[w2]);
    float cnt[NATOMS];
    #pragma unroll
    for(int a=0;a<NATOMS;a++){
        int c = 0;
        const unsigned* ia = &ind[a*64 + p*16];
        #pragma unroll
        for(int w2=0;w2<16;w2++) c += __popc(mw[w2] & ia[w2]);
        cnt[a] = (float)c;
    }
    #pragma unroll
    for(int a=0;a<NATOMS;a++){
        cnt[a] += __shfl_xor(cnt[a],1,64);
        cnt[a] += __shfl_xor(cnt[a],2,64);
    }
    float deg = (float)degi;
    deg += __shfl_xor(deg,1,64);
    deg += __shfl_xor(deg,2,64);

    // --- v = emb[own] + (sum_a cnt_a emb_a)/max(deg,1) -> global bf16 -------
    {
        float inv = 1.0f / fmaxf(deg, 1.0f);
        int oid = sid[tile*64 + node];
        int d0 = p*32;
        float vv[32];
        #pragma unroll
        for(int d=0;d<32;d++) vv[d]=0.f;
        #pragma unroll
        for(int a=0;a<NATOMS;a++){
            float ca = cnt[a];
            const float* ea = &emb[a*128 + d0];
            #pragma unroll
            for(int d=0;d<32;d+=4){
                float4 e = *(const float4*)&ea[d];
                vv[d]+=ca*e.x; vv[d+1]+=ca*e.y; vv[d+2]+=ca*e.z; vv[d+3]+=ca*e.w;
            }
        }
        const float* eo = &emb[oid*128 + d0];
        unsigned short* dst = vbf + (size_t)(row0+node)*128 + d0;
        #pragma unroll
        for(int d=0;d<32;d+=4){
            float4 e = *(const float4*)&eo[d];
            ushort4 o;
            o.x = f2b(e.x + vv[d]*inv);
            o.y = f2b(e.y + vv[d+1]*inv);
            o.z = f2b(e.z + vv[d+2]*inv);
            o.w = f2b(e.w + vv[d+3]*inv);
            *(ushort4*)&dst[d] = o;
        }
    }
}

// ---- Kernel 4b: hout GEMM + heads, gld16-staged MFMA operands --------------
// R14 showed the R5 pathology (VGPR 44, all pipes idle) from direct-global
// MFMA loads. Both K-loops now use the proven global_load_lds staging:
// hout GEMM stages A (v, 64x32) + B (Wm hi/lo, 128x32 each); t1 GEMM stages
// B (A1 hi/lo) only (A = houts already in LDS). LDS ~42.9 KiB -> 3 blocks/CU.
__global__ __launch_bounds__(256) void msgB_k(
    const unsigned short* __restrict__ vbf,
    const short* __restrict__ wmth, const short* __restrict__ wmtl,
    const float* __restrict__ b_msg, const float* __restrict__ w_coor,
    const short* __restrict__ a1th, const short* __restrict__ a1tl,
    const float* __restrict__ a1v, const float* __restrict__ A2,
    const float* __restrict__ a2v, const float* __restrict__ dalpha,
    const float* __restrict__ dw, const float* __restrict__ db,
    const float* __restrict__ coords, float* __restrict__ out_ang,
    float* __restrict__ out_z, float* __restrict__ out_co)
{
    __shared__ __align__(16) short sA[64*32];              // 4 KB A staging
    __shared__ __align__(16) short sBh[128*32], sBl[128*32]; // 8 KB each
    __shared__ unsigned short houts[64*136];   // hout bf16; later t1s [64][104]
    __shared__ float s_bm[128], s_wc[384], s_A2[624], s_a1[104];
    __shared__ float s_dyt[16], s_a2[8];
    int tid = threadIdx.x;
    int row0 = blockIdx.x*64;
    int lane = tid&63, w = tid>>6;
    int ln = lane&15, quad = lane>>4;
    int m0w = (w&1)*32, n0w = (w>>1)*64;
    int ar = tid>>2, kc = (tid&3)*8;           // staging coords

    // constants -> LDS (consumed only after the first in-loop barrier)
    if(tid<128) s_bm[tid] = b_msg[tid];
    if(tid<104) s_a1[tid] = (tid<ENCH) ? a1v[tid] : 0.f;
    for(int l=tid;l<384;l+=256) s_wc[l] = w_coor[l];
    for(int l=tid;l<624;l+=256) s_A2[l] = (l<600) ? A2[l] : 0.f;
    if(tid==0)  s_dyt[0] = dalpha[0];
    if(tid<6){ s_dyt[1+tid] = dw[tid]; s_dyt[8+tid] = db[tid]; }
    if(tid<8)  s_a2[tid] = (tid<6) ? a2v[tid] : 0.f;

    // ---- hout = gelu(v @ W_msg + b), 2-term W split, gld16 staging ---------
    f32x4 acc[2][4];
    #pragma unroll
    for(int i=0;i<2;i++)
        #pragma unroll
        for(int j=0;j<4;j++) acc[i][j] = (f32x4){0.f,0.f,0.f,0.f};
    for(int k0=0;k0<128;k0+=32){
        gld16(vbf + (size_t)(row0+ar)*128 + k0 + kc, &sA[tid*8]);
        #pragma unroll
        for(int i=0;i<2;i++){
            size_t go = (size_t)(i*64+ar)*128 + k0 + kc;
            gld16(wmth + go, &sBh[i*2048 + tid*8]);
            gld16(wmtl + go, &sBl[i*2048 + tid*8]);
        }
        __syncthreads();                 // vmcnt(0) drain -> tiles ready
        bf16x8 av[2];
        #pragma unroll
        for(int tm=0;tm<2;tm++)
            av[tm] = *(const bf16x8*)&sA[(m0w+tm*16+ln)*32 + quad*8];
        #pragma unroll
        for(int tn=0;tn<4;tn++){
            bf16x8 bh = *(const bf16x8*)&sBh[(n0w+tn*16+ln)*32 + quad*8];
            bf16x8 bl = *(const bf16x8*)&sBl[(n0w+tn*16+ln)*32 + quad*8];
            #pragma unroll
            for(int tm=0;tm<2;tm++){
                acc[tm][tn] = __builtin_amdgcn_mfma_f32_16x16x32_bf16(av[tm], bl, acc[tm][tn], 0,0,0);
                acc[tm][tn] = __builtin_amdgcn_mfma_f32_16x16x32_bf16(av[tm], bh, acc[tm][tn], 0,0,0);
            }
        }
        __syncthreads();                 // LDS reads done before next stage
    }
    // epilogue: z fp32 + hout bf16 to LDS
    #pragma unroll
    for(int tn=0;tn<4;tn++){
        int col = n0w + tn*16 + ln;
        float bias = s_bm[col];
        #pragma unroll
        for(int tm=0;tm<2;tm++){
            int mb2 = m0w + tm*16 + quad*4;
            #pragma unroll
            for(int r=0;r<4;r++){
                float hv = gelu_f(acc[tm][tn][r] + bias);
                out_z[(size_t)(row0+mb2+r)*128 + col] = hv;
                houts[(mb2+r)*136 + col] = f2b(hv);
            }
        }
    }
    __syncthreads();                    // houts ready

    int node = tid>>2, p = tid&3;
    // ---- coors: 4-lane k-split dot with w_coor -----------------------------
    {
        float d0=0.f, d1=0.f, d2=0.f;
        int kb = p*32;
        #pragma unroll
        for(int k=0;k<32;k+=4){
            ushort4 hv = *(const ushort4*)&houts[node*136 + kb + k];
            float h0=b2f(hv.x),h1=b2f(hv.y),h2=b2f(hv.z),h3=b2f(hv.w);
            const float* wc = &s_wc[(kb+k)*3];
            d0 += h0*wc[0]+h1*wc[3]+h2*wc[6]+h3*wc[9];
            d1 += h0*wc[1]+h1*wc[4]+h2*wc[7]+h3*wc[10];
            d2 += h0*wc[2]+h1*wc[5]+h2*wc[8]+h3*wc[11];
        }
        d0 += __shfl_xor(d0,1,64); d0 += __shfl_xor(d0,2,64);
        d1 += __shfl_xor(d1,1,64); d1 += __shfl_xor(d1,2,64);
        d2 += __shfl_xor(d2,1,64); d2 += __shfl_xor(d2,2,64);
        if(p==0){
            size_t o = (size_t)(row0+node)*3;
            out_co[o+0] = coords[o+0] + tanhf(d0);
            out_co[o+1] = coords[o+1] + tanhf(d1);
            out_co[o+2] = coords[o+2] + tanhf(d2);
        }
    }

    // ---- t1 = gelu(hout @ A1 + a1), 2-term split, gld16-staged B -----------
    f32x4 acc2[2][4];
    #pragma unroll
    for(int i=0;i<2;i++)
        #pragma unroll
        for(int j=0;j<4;j++) acc2[i][j] = (f32x4){0.f,0.f,0.f,0.f};
    for(int k0=0;k0<128;k0+=32){
        #pragma unroll
        for(int i=0;i<2;i++){
            size_t go = (size_t)(i*64+ar)*128 + k0 + kc;
            gld16(a1th + go, &sBh[i*2048 + tid*8]);
            gld16(a1tl + go, &sBl[i*2048 + tid*8]);
        }
        __syncthreads();
        bf16x8 ah[2];
        #pragma unroll
        for(int tm=0;tm<2;tm++)
            ah[tm] = *(const bf16x8*)&houts[(m0w+tm*16+ln)*136 + k0 + quad*8];
        #pragma unroll
        for(int tn=0;tn<4;tn++){
            bf16x8 bh = *(const bf16x8*)&sBh[(n0w+tn*16+ln)*32 + quad*8];
            bf16x8 bl = *(const bf16x8*)&sBl[(n0w+tn*16+ln)*32 + quad*8];
            #pragma unroll
            for(int tm=0;tm<2;tm++){
                acc2[tm][tn] = __builtin_amdgcn_mfma_f32_16x16x32_bf16(ah[tm], bl, acc2[tm][tn], 0,0,0);
                acc2[tm][tn] = __builtin_amdgcn_mfma_f32_16x16x32_bf16(ah[tm], bh, acc2[tm][tn], 0,0,0);
            }
        }
        __syncthreads();
    }
    unsigned short* t1s = houts;        // [64][104] (houts reads done)
    #pragma unroll
    for(int tn=0;tn<4;tn++){
        int col = n0w + tn*16 + ln;
        if(col < 104){
            float bias = s_a1[col];
            #pragma unroll
            for(int tm=0;tm<2;tm++){
                int mb2 = m0w + tm*16 + quad*4;
                #pragma unroll
                for(int r=0;r<4;r++)
                    t1s[(mb2+r)*104 + col] = f2b(gelu_f(acc2[tm][tn][r] + bias));
            }
        }
    }
    __syncthreads();

    // ---- t2 = gelu(t1@A2+a2); DyT; angles ----------------------------------
    {
        int g0 = (p<2) ? p*7 : 14+(p-2)*6;
        int gcount = (p<2) ? 7 : 6;
        float s[6] = {0.f,0.f,0.f,0.f,0.f,0.f};
        for(int gg=0; gg<gcount; gg++){
            int kb = (g0+gg)*4;
            ushort4 tv = *(const ushort4*)&t1s[node*104 + kb];
            float u0=b2f(tv.x), u1=b2f(tv.y), u2=b2f(tv.z), u3=b2f(tv.w);
            #pragma unroll
            for(int j=0;j<6;j++)
                s[j] += u0*s_A2[kb*6+j] + u1*s_A2[(kb+1)*6+j]
                      + u2*s_A2[(kb+2)*6+j] + u3*s_A2[(kb+3)*6+j];
        }
        #pragma unroll
        for(int j=0;j<6;j++){ s[j]+=__shfl_xor(s[j],1,64); s[j]+=__shfl_xor(s[j],2,64); }
        if(p<2){
            size_t o = (size_t)(row0+node)*6 + p*3;
            #pragma unroll
            for(int jj=0;jj<3;jj++){
                int j = p*3+jj;
                float t2v = gelu_f(s[j] + s_a2[j]);
                float uu = tanhf(s_dyt[0]*t2v)*s_dyt[1+j] + s_dyt[8+j];
                out_ang[o+jj] = tanhf(uu);
            }
        }
    }
}

// ---------------------------------------------------------------------------
extern "C" void kernel_launch(void* const* d_in, const int* in_sizes, int n_in,
                              void* d_out, int out_size, void* d_ws, size_t ws_size,
                              hipStream_t stream) {
    const float* x      = (const float*)d_in[0];
    const float* coords = (const float*)d_in[1];
    const int*   ei     = (const int*)d_in[2];
    const float* gamma  = (const float*)d_in[4];
    const float* beta   = (const float*)d_in[5];
    const float* W1     = (const float*)d_in[6];
    const float* b1     = (const float*)d_in[7];
    const float* W2     = (const float*)d_in[8];
    const float* b2     = (const float*)d_in[9];
    const float* W3     = (const float*)d_in[10];
    const float* b3     = (const float*)d_in[11];
    const float* embed  = (const float*)d_in[12];
    const float* W_msg  = (const float*)d_in[13];
    const float* b_msg  = (const float*)d_in[14];
    const float* w_coor = (const float*)d_in[15];
    const float* A1     = (const float*)d_in[16];
    const float* a1v    = (const float*)d_in[17];
    const float* A2     = (const float*)d_in[18];
    const float* a2v    = (const float*)d_in[19];
    const float* dalpha = (const float*)d_in[20];
    const float* dw     = (const float*)d_in[21];
    const float* db     = (const float*)d_in[22];

    // ws layout (~44 MB peak):
    //  0      : ids   (128 KB)
    //  128K   : stats (2 KB) + ecnt (2 KB)   <- one 4 KB memset
    //  256K   : weight planes (512 KB) + b1p (1 KB)
    //  1M     : earena u32[512*3072] (6 MB)
    //  10M    : x-hi -> overwritten in-place by h1h -> reused as v bf16
    //  27M    : x-lo -> overwritten in-place by h1l
    char* ws = (char*)d_ws;
    int*      ids   = (int*)ws;
    float*    stats = (float*)(ws + 131072);
    unsigned* ecnt  = (unsigned*)(ws + 131072 + 2048);
    short*    w1th  = (short*)(ws + 262144);
    short*    w1tl  = w1th + 65536;
    short*    w2th  = w1tl + 65536;
    short*    w2tl  = w2th + 32768;
    short*    wmth  = w2tl + 32768;
    short*    wmtl  = wmth + 16384;
    short*    a1th  = wmtl + 16384;
    short*    a1tl  = a1th + 16384;
    float*    b1p   = (float*)(a1tl + 16384);
    unsigned* earena = (unsigned*)(ws + (1<<20));
    unsigned short* h1h = (unsigned short*)(ws + (size_t)10*1048576);
    unsigned short* h1l = (unsigned short*)(ws + (size_t)27*1048576);
    unsigned short* vbf = h1h;   // h1 planes dead after gemm23 -> reuse for v

    float* out_ang = (float*)d_out;
    float* out_z   = out_ang + (size_t)NT*OUTC;
    float* out_co  = out_z   + (size_t)NT*DIMd;

    hipMemsetAsync(stats, 0, 4096, stream);      // stats + ecnt
    prep0_k<<<832, 256, 0, stream>>>(x, stats, W2, W_msg, A1,
        w2th, w2tl, wmth, wmtl, a1th, a1tl, h1h, h1l, ei, ecnt, earena);
    prep1_k<<<65, 256, 0, stream>>>(stats, gamma, beta, W1, b1,
        w1th, w1tl, b1p);
    gemm1_k<<<512, 256, 0, stream>>>(h1h, h1l, w1th, w1tl, b1p);
    gemm23_mfma<<<512, 256, 0, stream>>>(h1h, h1l, w2th, w2tl, b2, W3, b3, ids);
    msgA_k<<<512, 256, 0, stream>>>(ids, ecnt, earena, embed, vbf);
    msgB_k<<<512, 256, 0, stream>>>(vbf, wmth, wmtl, b_msg, w_coor,
        a1th, a1tl, a1v, A2, a2v, dalpha, dw, db, coords,
        out_ang, out_z, out_co);
}

// Round 17
// 255.431 us; speedup vs baseline: 1.4441x; 1.4421x over previous
//
#include <hip/hip_runtime.h>
#include <hip/hip_bf16.h>
#include <math.h>

// Problem constants (match reference)
#define Bg 16
#define Nn 2048
#define Ee (1<<20)
#define NT (Bg*Nn)
#define INC 256
#define DIMd 128
#define OUTC 6
#define ENCH 100
#define NATOMS 20
#define BINCAP 3072   // per-bin edge capacity: mean 2048, sigma~44 -> +23 sigma

typedef __attribute__((ext_vector_type(8))) short bf16x8;
typedef __attribute__((ext_vector_type(4))) float f32x4;

__device__ __forceinline__ float gelu_f(float x){
    return 0.5f*x*(1.0f+erff(x*0.70710678118654752440f));
}
__device__ __forceinline__ unsigned short f2b(float f){
    __hip_bfloat16 h = __float2bfloat16(f);
    return *(unsigned short*)&h;
}
__device__ __forceinline__ float b2f(unsigned short u){
    unsigned v = ((unsigned)u)<<16;
    return __uint_as_float(v);
}
// split fp32 into bf16 hi + bf16 lo (v ~= hi + lo, dropped residual ~2^-18 rel)
__device__ __forceinline__ void splitf(float v, unsigned short& hi, unsigned short& lo){
    unsigned short h = f2b(v);
    hi = h; lo = f2b(v - b2f(h));
}
// async global->LDS, 16B per lane. LDS dest = per-lane ptr matching
// wave-uniform-base + lane*16 layout (m97 pattern).
__device__ __forceinline__ void gld16(const void* g, void* l){
    __builtin_amdgcn_global_load_lds(
        (const __attribute__((address_space(1))) unsigned*)g,
        (__attribute__((address_space(3))) unsigned*)l, 16, 0, 0);
}

// ---- Kernel 1: prep0 ------------------------------------------------------
// TAIL-FIRST block ordering (R11 showed a serial tail: scatter/wsplit blocks
// dispatched last ran at 0.75 blocks/CU after streaming finished -> 45 us).
//  blocks 0..255  : edge bucket-scatter, 4096 edges each
//  blocks 256..319: W2/Wm/A1 weight splits
//  blocks 320..831: BN stats + RAW x hi/lo split, 64 rows/block, float4 loads
__global__ __launch_bounds__(256) void prep0_k(const float* __restrict__ x,
    float* __restrict__ stats, const float* __restrict__ W2,
    const float* __restrict__ Wm, const float* __restrict__ A1,
    short* __restrict__ w2th, short* __restrict__ w2tl,
    short* __restrict__ wmth, short* __restrict__ wmtl,
    short* __restrict__ a1th, short* __restrict__ a1tl,
    unsigned short* __restrict__ xh, unsigned short* __restrict__ xl,
    const int* __restrict__ ei, unsigned* __restrict__ ecnt,
    unsigned* __restrict__ earena)
{
    __shared__ float sp1[4*256], sp2[4*256];     // 8 KB stats partials
    __shared__ unsigned scat[1024];
    int bx = blockIdx.x, tid = threadIdx.x;
    if(bx < 256){
        // ---- edge bucket-scatter (256 blocks; 4096 edges each) ------------
        unsigned* lcnt  = scat;              // 512 u32
        unsigned* gbase = scat + 512;
        for(int l=tid; l<512; l+=256) lcnt[l] = 0;
        __syncthreads();
        int ebase = bx * 4096;
        #pragma unroll 8
        for(int i=0;i<16;i++){
            int e = ebase + i*256 + tid;
            int s = ei[e], d = ei[Ee+e];
            if((s>>11)==(d>>11)) atomicAdd(&lcnt[s>>6], 1u);
        }
        __syncthreads();
        for(int l=tid; l<512; l+=256){
            unsigned c = lcnt[l];
            gbase[l] = c ? atomicAdd(&ecnt[l], c) : 0u;
            lcnt[l] = 0;
        }
        __syncthreads();
        #pragma unroll 8
        for(int i=0;i<16;i++){
            int e = ebase + i*256 + tid;
            int s = ei[e], d = ei[Ee+e];
            if((s>>11)==(d>>11)){
                int bin = s>>6;
                unsigned r = atomicAdd(&lcnt[bin], 1u);
                unsigned pos = gbase[bin] + r;
                if(pos < BINCAP)
                    earena[(size_t)bin*BINCAP + pos] =
                        ((unsigned)(s&63)<<11) | (unsigned)(d&2047);
            }
        }
    } else if(bx < 320){
        int gid = (bx-256)*256 + tid;             // 64 blocks -> 16384 threads
        unsigned short hi, lo;
        for(int l=gid;l<32768;l+=16384){ int n=l>>8,k=l&255;
            splitf(W2[(size_t)k*128+n],hi,lo); w2th[l]=(short)hi; w2tl[l]=(short)lo; }
        for(int l=gid;l<16384;l+=16384){ int n=l>>7,k=l&127;
            splitf(Wm[(size_t)k*128+n],hi,lo); wmth[l]=(short)hi; wmtl[l]=(short)lo; }
        for(int l=gid;l<16384;l+=16384){ int n=l>>7,k=l&127;
            float v=(n<ENCH)? A1[(size_t)k*ENCH+n] : 0.f;
            splitf(v,hi,lo); a1th[l]=(short)hi; a1tl[l]=(short)lo; }
    } else {
        int cg = (tid&63)*4;                     // 4-col group
        int rr = tid>>6;                         // row phase 0..3
        int r0 = (bx-320)*64;
        float s0=0,s1=0,s2=0,s3=0, q0=0,q1=0,q2=0,q3=0;
        #pragma unroll
        for(int i=0;i<16;i++){
            int r = r0 + rr + i*4;
            size_t off = (size_t)r*INC + cg;
            float4 v = *(const float4*)&x[off];
            ushort4 hi, lo;
            splitf(v.x,hi.x,lo.x); splitf(v.y,hi.y,lo.y);
            splitf(v.z,hi.z,lo.z); splitf(v.w,hi.w,lo.w);
            *(ushort4*)&xh[off] = hi;
            *(ushort4*)&xl[off] = lo;
            s0+=v.x; s1+=v.y; s2+=v.z; s3+=v.w;
            q0+=v.x*v.x; q1+=v.y*v.y; q2+=v.z*v.z; q3+=v.w*v.w;
        }
        sp1[rr*256+cg]=s0; sp1[rr*256+cg+1]=s1;
        sp1[rr*256+cg+2]=s2; sp1[rr*256+cg+3]=s3;
        sp2[rr*256+cg]=q0; sp2[rr*256+cg+1]=q1;
        sp2[rr*256+cg+2]=q2; sp2[rr*256+cg+3]=q3;
        __syncthreads();
        {
            float a = sp1[tid]+sp1[256+tid]+sp1[512+tid]+sp1[768+tid];
            float b = sp2[tid]+sp2[256+tid]+sp2[512+tid]+sp2[768+tid];
            atomicAdd(&stats[tid], a);
            atomicAdd(&stats[INC+tid], b);
        }
    }
}

// ---- Kernel 1c: prep1 = BN fold. W1' = s*W1 -> hi/lo planes (blocks 0..63);
//                 b1' = b1 + t@W1 (block 64). Runs after stats complete.
__global__ __launch_bounds__(256) void prep1_k(const float* __restrict__ stats,
    const float* __restrict__ gamma, const float* __restrict__ beta,
    const float* __restrict__ W1, const float* __restrict__ b1,
    short* __restrict__ w1th, short* __restrict__ w1tl, float* __restrict__ b1p)
{
    __shared__ float sc[256], sh[256];
    int bx = blockIdx.x, tid = threadIdx.x;
    {
        float mu  = stats[tid]*(1.0f/NT);
        float var = stats[256+tid]*(1.0f/NT) - mu*mu;
        float s = gamma[tid]/sqrtf(var + 1e-5f);
        sc[tid] = s; sh[tid] = beta[tid] - mu*s;
    }
    __syncthreads();
    if(bx < 64){
        int gid = bx*256 + tid;
        unsigned short hi, lo;
        for(int l=gid;l<65536;l+=16384){ int n=l>>8,k=l&255;
            splitf(sc[k]*W1[(size_t)k*256+n],hi,lo);
            w1th[l]=(short)hi; w1tl[l]=(short)lo; }
    } else {
        float acc = b1[tid];
        for(int k=0;k<256;k++) acc += sh[k]*W1[(size_t)k*256+tid];
        b1p[tid] = acc;
    }
}

// ---- Kernel 2: h1 = gelu(x@W1'+b1'), 64x256 tile, BK=64, 3-term split -----
// R15: gemm1 top kernel, grid-limited to 2 blocks/CU with a vmcnt(0) drain
// per K-step. BK 32->64 halves the drain count (8->4 barrier pairs). Each
// 64-k tile is staged as TWO 32-wide sub-tiles (row stride stays 64 B; a
// fused [r][64] layout would align rows to the 128 B bank period -> 16-way
// conflicts). LDS 80 KiB -> 2 blocks/CU = grid limit, so no occupancy loss.
__global__ __launch_bounds__(256) void gemm1_k(
    unsigned short* xh, unsigned short* xl,
    const short* __restrict__ w1th, const short* __restrict__ w1tl,
    const float* __restrict__ b1p)
{
    __shared__ __align__(16) short sAh[2][64*32], sAl[2][64*32];   // 4 KB each
    __shared__ __align__(16) short sBh[2][256*32], sBl[2][256*32]; // 16 KB each
    int tid = threadIdx.x;
    int row0 = blockIdx.x*64;
    int lane = tid&63, w = tid>>6;
    int ln = lane&15, quad = lane>>4;
    int m0w = (w&1)*32, n0b = (w>>1)*128;
    int ar = tid>>2, kc = (tid&3)*8;             // staging coords
    f32x4 acc[2][8];
    #pragma unroll
    for(int i=0;i<2;i++)
        #pragma unroll
        for(int j=0;j<8;j++) acc[i][j] = (f32x4){0.f,0.f,0.f,0.f};

    for(int k0=0;k0<256;k0+=64){
        #pragma unroll
        for(int h=0;h<2;h++){
            int kb = k0 + 32*h;
            // A: 64 rows x 32 k, 1 issue per plane per half
            gld16(xh + (size_t)(row0+ar)*256 + kb + kc, &sAh[h][tid*8]);
            gld16(xl + (size_t)(row0+ar)*256 + kb + kc, &sAl[h][tid*8]);
            // B: 256 rows x 32 k, 4 issues per plane per half
            #pragma unroll
            for(int i=0;i<4;i++){
                size_t go = (size_t)(i*64+ar)*256 + kb + kc;
                gld16(w1th + go, &sBh[h][i*2048 + tid*8]);
                gld16(w1tl + go, &sBl[h][i*2048 + tid*8]);
            }
        }
        __syncthreads();                 // vmcnt(0) drain -> both halves ready
        #pragma unroll
        for(int h=0;h<2;h++){
            bf16x8 ah[2], al[2];
            #pragma unroll
            for(int tm=0;tm<2;tm++){
                ah[tm] = *(const bf16x8*)&sAh[h][(m0w+tm*16+ln)*32 + quad*8];
                al[tm] = *(const bf16x8*)&sAl[h][(m0w+tm*16+ln)*32 + quad*8];
            }
            #pragma unroll
            for(int tn=0;tn<8;tn++){
                bf16x8 bh = *(const bf16x8*)&sBh[h][(n0b+tn*16+ln)*32 + quad*8];
                bf16x8 bl = *(const bf16x8*)&sBl[h][(n0b+tn*16+ln)*32 + quad*8];
                #pragma unroll
                for(int tm=0;tm<2;tm++){
                    acc[tm][tn] = __builtin_amdgcn_mfma_f32_16x16x32_bf16(al[tm], bh, acc[tm][tn], 0,0,0);
                    acc[tm][tn] = __builtin_amdgcn_mfma_f32_16x16x32_bf16(ah[tm], bl, acc[tm][tn], 0,0,0);
                    acc[tm][tn] = __builtin_amdgcn_mfma_f32_16x16x32_bf16(ah[tm], bh, acc[tm][tn], 0,0,0);
                }
            }
        }
        __syncthreads();                 // LDS reads done before next stage
    }
    #pragma unroll
    for(int tn=0;tn<8;tn++){
        int col = n0b + tn*16 + ln;
        float bias = b1p[col];
        #pragma unroll
        for(int tm=0;tm<2;tm++){
            int rowb = row0 + m0w + tm*16 + quad*4;
            #pragma unroll
            for(int r=0;r<4;r++){
                float hv = gelu_f(acc[tm][tn][r] + bias);
                unsigned short hi, lo;
                splitf(hv, hi, lo);
                xh[(size_t)(rowb+r)*256 + col] = hi;     // h1 overwrites x
                xl[(size_t)(rowb+r)*256 + col] = lo;
            }
        }
    }
}

// ------ Kernel 3: h2=gelu(h1@W2+b2) via global_load_lds staging; -----------
// logits+argmax in-block. grid 512, 4 waves, wave=32m x 64n. h2s/w3s overlay
// the dead staging arena after the GEMM loop.
__global__ __launch_bounds__(256) void gemm23_mfma(
    const unsigned short* __restrict__ h1h, const unsigned short* __restrict__ h1l,
    const short* __restrict__ w2th, const short* __restrict__ w2tl,
    const float* __restrict__ b2, const float* __restrict__ W3,
    const float* __restrict__ b3, int* __restrict__ ids)
{
    __shared__ __align__(16) char arena[44032];
    short* sAh = (short*)arena;                 // 4096 B
    short* sAl = (short*)(arena + 4096);        // 4096 B
    short* sBh = (short*)(arena + 8192);        // 8192 B
    short* sBl = (short*)(arena + 16384);       // 8192 B
    float* h2s = (float*)arena;                 // 64*132 f32 = 33792 B
    float* w3s = (float*)(arena + 33792);       // 2560 f32 = 10240 B
    __shared__ float lgs[64*20];
    int tid = threadIdx.x;
    int row0 = blockIdx.x*64;
    int lane = tid&63, w = tid>>6;
    int ln = lane&15, quad = lane>>4;
    int m0w = (w&1)*32, n0w = (w>>1)*64;
    int ar = tid>>2, kc = (tid&3)*8;
    f32x4 acc[2][4];
    #pragma unroll
    for(int i=0;i<2;i++)
        #pragma unroll
        for(int j=0;j<4;j++) acc[i][j] = (f32x4){0.f,0.f,0.f,0.f};

    for(int k0=0;k0<256;k0+=32){
        gld16(h1h + (size_t)(row0+ar)*256 + k0 + kc, &sAh[tid*8]);
        gld16(h1l + (size_t)(row0+ar)*256 + k0 + kc, &sAl[tid*8]);
        #pragma unroll
        for(int i=0;i<2;i++){
            size_t go = (size_t)(i*64+ar)*256 + k0 + kc;
            gld16(w2th + go, &sBh[i*2048 + tid*8]);
            gld16(w2tl + go, &sBl[i*2048 + tid*8]);
        }
        __syncthreads();
        bf16x8 ah[2], al[2];
        #pragma unroll
        for(int tm=0;tm<2;tm++){
            ah[tm] = *(const bf16x8*)&sAh[(m0w+tm*16+ln)*32 + quad*8];
            al[tm] = *(const bf16x8*)&sAl[(m0w+tm*16+ln)*32 + quad*8];
        }
        #pragma unroll
        for(int tn=0;tn<4;tn++){
            bf16x8 bh = *(const bf16x8*)&sBh[(n0w+tn*16+ln)*32 + quad*8];
            bf16x8 bl = *(const bf16x8*)&sBl[(n0w+tn*16+ln)*32 + quad*8];
            #pragma unroll
            for(int tm=0;tm<2;tm++){
                acc[tm][tn] = __builtin_amdgcn_mfma_f32_16x16x32_bf16(al[tm], bh, acc[tm][tn], 0,0,0);
                acc[tm][tn] = __builtin_amdgcn_mfma_f32_16x16x32_bf16(ah[tm], bl, acc[tm][tn], 0,0,0);
                acc[tm][tn] = __builtin_amdgcn_mfma_f32_16x16x32_bf16(ah[tm], bh, acc[tm][tn], 0,0,0);
            }
        }
        __syncthreads();                 // staging arena dead after last iter
    }
    // epilogue: h2 -> overlaid LDS
    #pragma unroll
    for(int tn=0;tn<4;tn++){
        int col = n0w + tn*16 + ln;
        float bias = b2[col];
        #pragma unroll
        for(int tm=0;tm<2;tm++){
            int rb = m0w + tm*16 + quad*4;
            #pragma unroll
            for(int r=0;r<4;r++)
                h2s[(rb+r)*132 + col] = gelu_f(acc[tm][tn][r] + bias);
        }
    }
    for(int l=tid;l<2560;l+=256) w3s[l] = W3[l];
    __syncthreads();
    int n = tid>>2, q = tid&3;
    float lg[5] = {};
    #pragma unroll 4
    for(int k=0;k<128;k++){
        float h = h2s[n*132+k];
        #pragma unroll
        for(int a=0;a<5;a++) lg[a] += h*w3s[k*20 + q*5 + a];
    }
    #pragma unroll
    for(int a=0;a<5;a++) lgs[n*20 + q*5 + a] = lg[a] + b3[q*5+a];
    __syncthreads();
    if(tid<64){                                     // numpy argmax: first max wins
        float best = lgs[tid*20]; int bi = 0;
        #pragma unroll
        for(int a=1;a<20;a++){ float v2 = lgs[tid*20+a]; if(v2>best){best=v2;bi=a;} }
        ids[row0+tid] = bi;
    }
}

// ---- Kernel 4a: aggregation only -> v bf16 to workspace --------------------
// grid 512 bins x 256. LDS 33.8 KiB -> 4 blocks/CU. 3 barriers total.
__global__ __launch_bounds__(256) void msgA_k(
    const int* __restrict__ ids, const unsigned* __restrict__ ecnt,
    const unsigned* __restrict__ earena, const float* __restrict__ embed,
    unsigned short* __restrict__ vbf)
{
    __shared__ unsigned lmask[64*64];          // 16 KiB dst bitmask per node
    __shared__ unsigned ind[NATOMS*64];        // 5 KiB indicator bitmasks
    __shared__ unsigned char sid[2048];        // atom id per graph node
    __shared__ float emb[NATOMS*128];          // 10 KiB embedding table
    int tid = threadIdx.x;
    int bin = blockIdx.x;
    int row0 = bin*64;
    int g = bin>>5, tile = bin&31;
    int lane = tid&63, w = tid>>6;

    // --- phase 0 ------------------------------------------------------------
    for(int l=tid;l<NATOMS*128;l+=256) emb[l] = embed[l];
    #pragma unroll
    for(int i=0;i<8;i++){ int j = tid + i*256; sid[j] = (unsigned char)ids[g*Nn + j]; }
    #pragma unroll
    for(int i=0;i<16;i++) lmask[tid + i*256] = 0;
    int nb = min((int)ecnt[bin], BINCAP);
    __syncthreads();

    // --- phase 1: ballot indicator bitmasks + LDS adjacency build -----------
    for(int wp=w; wp<32; wp+=4){
        int a = sid[wp*64 + lane];
        #pragma unroll
        for(int atom=0; atom<NATOMS; atom++){
            unsigned long long bm = __ballot(a==atom);
            if(lane<2) ind[atom*64 + wp*2 + lane] = (unsigned)(bm >> (32*lane));
        }
    }
    for(int i=tid; i<nb; i+=256){
        unsigned wv = earena[(size_t)bin*BINCAP + i];
        int sl = wv>>11, dl = wv & 2047;
        atomicOr(&lmask[sl*64 + (dl>>5)], 1u<<(dl&31));
    }
    __syncthreads();

    // --- phase 2: per-node counts popcount(lmask & ind), 4-lane split -------
    int node = tid>>2, p = tid&3;
    unsigned mw[16];
    {
        const unsigned* mrow = &lmask[node*64 + p*16];
        *(uint4*)&mw[0]  = *(const uint4*)&mrow[0];
        *(uint4*)&mw[4]  = *(const uint4*)&mrow[4];
        *(uint4*)&mw[8]  = *(const uint4*)&mrow[8];
        *(uint4*)&mw[12] = *(const uint4*)&mrow[12];
    }
    int degi = 0;
    #pragma unroll
    for(int w2=0;w2<16;w2++) degi += __popc(mw[w2]);
    float cnt[NATOMS];
    #pragma unroll
    for(int a=0;a<NATOMS;a++){
        int c = 0;
        const unsigned* ia = &ind[a*64 + p*16];
        #pragma unroll
        for(int w2=0;w2<16;w2++) c += __popc(mw[w2] & ia[w2]);
        cnt[a] = (float)c;
    }
    #pragma unroll
    for(int a=0;a<NATOMS;a++){
        cnt[a] += __shfl_xor(cnt[a],1,64);
        cnt[a] += __shfl_xor(cnt[a],2,64);
    }
    float deg = (float)degi;
    deg += __shfl_xor(deg,1,64);
    deg += __shfl_xor(deg,2,64);

    // --- v = emb[own] + (sum_a cnt_a emb_a)/max(deg,1) -> global bf16 -------
    {
        float inv = 1.0f / fmaxf(deg, 1.0f);
        int oid = sid[tile*64 + node];
        int d0 = p*32;
        float vv[32];
        #pragma unroll
        for(int d=0;d<32;d++) vv[d]=0.f;
        #pragma unroll
        for(int a=0;a<NATOMS;a++){
            float ca = cnt[a];
            const float* ea = &emb[a*128 + d0];
            #pragma unroll
            for(int d=0;d<32;d+=4){
                float4 e = *(const float4*)&ea[d];
                vv[d]+=ca*e.x; vv[d+1]+=ca*e.y; vv[d+2]+=ca*e.z; vv[d+3]+=ca*e.w;
            }
        }
        const float* eo = &emb[oid*128 + d0];
        unsigned short* dst = vbf + (size_t)(row0+node)*128 + d0;
        #pragma unroll
        for(int d=0;d<32;d+=4){
            float4 e = *(const float4*)&eo[d];
            ushort4 o;
            o.x = f2b(e.x + vv[d]*inv);
            o.y = f2b(e.y + vv[d+1]*inv);
            o.z = f2b(e.z + vv[d+2]*inv);
            o.w = f2b(e.w + vv[d+3]*inv);
            *(ushort4*)&dst[d] = o;
        }
    }
}

// ---- Kernel 4b: hout GEMM + heads, gld16-staged MFMA operands --------------
// hout GEMM stages A (v, 64x32) + B (Wm hi/lo, 128x32 each); t1 GEMM stages
// B (A1 hi/lo) only (A = houts already in LDS). LDS ~42.9 KiB -> 3 blocks/CU.
__global__ __launch_bounds__(256) void msgB_k(
    const unsigned short* __restrict__ vbf,
    const short* __restrict__ wmth, const short* __restrict__ wmtl,
    const float* __restrict__ b_msg, const float* __restrict__ w_coor,
    const short* __restrict__ a1th, const short* __restrict__ a1tl,
    const float* __restrict__ a1v, const float* __restrict__ A2,
    const float* __restrict__ a2v, const float* __restrict__ dalpha,
    const float* __restrict__ dw, const float* __restrict__ db,
    const float* __restrict__ coords, float* __restrict__ out_ang,
    float* __restrict__ out_z, float* __restrict__ out_co)
{
    __shared__ __align__(16) short sA[64*32];              // 4 KB A staging
    __shared__ __align__(16) short sBh[128*32], sBl[128*32]; // 8 KB each
    __shared__ unsigned short houts[64*136];   // hout bf16; later t1s [64][104]
    __shared__ float s_bm[128], s_wc[384], s_A2[624], s_a1[104];
    __shared__ float s_dyt[16], s_a2[8];
    int tid = threadIdx.x;
    int row0 = blockIdx.x*64;
    int lane = tid&63, w = tid>>6;
    int ln = lane&15, quad = lane>>4;
    int m0w = (w&1)*32, n0w = (w>>1)*64;
    int ar = tid>>2, kc = (tid&3)*8;           // staging coords

    // constants -> LDS (consumed only after the first in-loop barrier)
    if(tid<128) s_bm[tid] = b_msg[tid];
    if(tid<104) s_a1[tid] = (tid<ENCH) ? a1v[tid] : 0.f;
    for(int l=tid;l<384;l+=256) s_wc[l] = w_coor[l];
    for(int l=tid;l<624;l+=256) s_A2[l] = (l<600) ? A2[l] : 0.f;
    if(tid==0)  s_dyt[0] = dalpha[0];
    if(tid<6){ s_dyt[1+tid] = dw[tid]; s_dyt[8+tid] = db[tid]; }
    if(tid<8)  s_a2[tid] = (tid<6) ? a2v[tid] : 0.f;

    // ---- hout = gelu(v @ W_msg + b), 2-term W split, gld16 staging ---------
    f32x4 acc[2][4];
    #pragma unroll
    for(int i=0;i<2;i++)
        #pragma unroll
        for(int j=0;j<4;j++) acc[i][j] = (f32x4){0.f,0.f,0.f,0.f};
    for(int k0=0;k0<128;k0+=32){
        gld16(vbf + (size_t)(row0+ar)*128 + k0 + kc, &sA[tid*8]);
        #pragma unroll
        for(int i=0;i<2;i++){
            size_t go = (size_t)(i*64+ar)*128 + k0 + kc;
            gld16(wmth + go, &sBh[i*2048 + tid*8]);
            gld16(wmtl + go, &sBl[i*2048 + tid*8]);
        }
        __syncthreads();                 // vmcnt(0) drain -> tiles ready
        bf16x8 av[2];
        #pragma unroll
        for(int tm=0;tm<2;tm++)
            av[tm] = *(const bf16x8*)&sA[(m0w+tm*16+ln)*32 + quad*8];
        #pragma unroll
        for(int tn=0;tn<4;tn++){
            bf16x8 bh = *(const bf16x8*)&sBh[(n0w+tn*16+ln)*32 + quad*8];
            bf16x8 bl = *(const bf16x8*)&sBl[(n0w+tn*16+ln)*32 + quad*8];
            #pragma unroll
            for(int tm=0;tm<2;tm++){
                acc[tm][tn] = __builtin_amdgcn_mfma_f32_16x16x32_bf16(av[tm], bl, acc[tm][tn], 0,0,0);
                acc[tm][tn] = __builtin_amdgcn_mfma_f32_16x16x32_bf16(av[tm], bh, acc[tm][tn], 0,0,0);
            }
        }
        __syncthreads();                 // LDS reads done before next stage
    }
    // epilogue: z fp32 + hout bf16 to LDS
    #pragma unroll
    for(int tn=0;tn<4;tn++){
        int col = n0w + tn*16 + ln;
        float bias = s_bm[col];
        #pragma unroll
        for(int tm=0;tm<2;tm++){
            int mb2 = m0w + tm*16 + quad*4;
            #pragma unroll
            for(int r=0;r<4;r++){
                float hv = gelu_f(acc[tm][tn][r] + bias);
                out_z[(size_t)(row0+mb2+r)*128 + col] = hv;
                houts[(mb2+r)*136 + col] = f2b(hv);
            }
        }
    }
    __syncthreads();                    // houts ready

    int node = tid>>2, p = tid&3;
    // ---- coors: 4-lane k-split dot with w_coor -----------------------------
    {
        float d0=0.f, d1=0.f, d2=0.f;
        int kb = p*32;
        #pragma unroll
        for(int k=0;k<32;k+=4){
            ushort4 hv = *(const ushort4*)&houts[node*136 + kb + k];
            float h0=b2f(hv.x),h1=b2f(hv.y),h2=b2f(hv.z),h3=b2f(hv.w);
            const float* wc = &s_wc[(kb+k)*3];
            d0 += h0*wc[0]+h1*wc[3]+h2*wc[6]+h3*wc[9];
            d1 += h0*wc[1]+h1*wc[4]+h2*wc[7]+h3*wc[10];
            d2 += h0*wc[2]+h1*wc[5]+h2*wc[8]+h3*wc[11];
        }
        d0 += __shfl_xor(d0,1,64); d0 += __shfl_xor(d0,2,64);
        d1 += __shfl_xor(d1,1,64); d1 += __shfl_xor(d1,2,64);
        d2 += __shfl_xor(d2,1,64); d2 += __shfl_xor(d2,2,64);
        if(p==0){
            size_t o = (size_t)(row0+node)*3;
            out_co[o+0] = coords[o+0] + tanhf(d0);
            out_co[o+1] = coords[o+1] + tanhf(d1);
            out_co[o+2] = coords[o+2] + tanhf(d2);
        }
    }

    // ---- t1 = gelu(hout @ A1 + a1), 2-term split, gld16-staged B -----------
    f32x4 acc2[2][4];
    #pragma unroll
    for(int i=0;i<2;i++)
        #pragma unroll
        for(int j=0;j<4;j++) acc2[i][j] = (f32x4){0.f,0.f,0.f,0.f};
    for(int k0=0;k0<128;k0+=32){
        #pragma unroll
        for(int i=0;i<2;i++){
            size_t go = (size_t)(i*64+ar)*128 + k0 + kc;
            gld16(a1th + go, &sBh[i*2048 + tid*8]);
            gld16(a1tl + go, &sBl[i*2048 + tid*8]);
        }
        __syncthreads();
        bf16x8 ah[2];
        #pragma unroll
        for(int tm=0;tm<2;tm++)
            ah[tm] = *(const bf16x8*)&houts[(m0w+tm*16+ln)*136 + k0 + quad*8];
        #pragma unroll
        for(int tn=0;tn<4;tn++){
            bf16x8 bh = *(const bf16x8*)&sBh[(n0w+tn*16+ln)*32 + quad*8];
            bf16x8 bl = *(const bf16x8*)&sBl[(n0w+tn*16+ln)*32 + quad*8];
            #pragma unroll
            for(int tm=0;tm<2;tm++){
                acc2[tm][tn] = __builtin_amdgcn_mfma_f32_16x16x32_bf16(ah[tm], bl, acc2[tm][tn], 0,0,0);
                acc2[tm][tn] = __builtin_amdgcn_mfma_f32_16x16x32_bf16(ah[tm], bh, acc2[tm][tn], 0,0,0);
            }
        }
        __syncthreads();
    }
    unsigned short* t1s = houts;        // [64][104] (houts reads done)
    #pragma unroll
    for(int tn=0;tn<4;tn++){
        int col = n0w + tn*16 + ln;
        if(col < 104){
            float bias = s_a1[col];
            #pragma unroll
            for(int tm=0;tm<2;tm++){
                int mb2 = m0w + tm*16 + quad*4;
                #pragma unroll
                for(int r=0;r<4;r++)
                    t1s[(mb2+r)*104 + col] = f2b(gelu_f(acc2[tm][tn][r] + bias));
            }
        }
    }
    __syncthreads();

    // ---- t2 = gelu(t1@A2+a2); DyT; angles ----------------------------------
    {
        int g0 = (p<2) ? p*7 : 14+(p-2)*6;
        int gcount = (p<2) ? 7 : 6;
        float s[6] = {0.f,0.f,0.f,0.f,0.f,0.f};
        for(int gg=0; gg<gcount; gg++){
            int kb = (g0+gg)*4;
            ushort4 tv = *(const ushort4*)&t1s[node*104 + kb];
            float u0=b2f(tv.x), u1=b2f(tv.y), u2=b2f(tv.z), u3=b2f(tv.w);
            #pragma unroll
            for(int j=0;j<6;j++)
                s[j] += u0*s_A2[kb*6+j] + u1*s_A2[(kb+1)*6+j]
                      + u2*s_A2[(kb+2)*6+j] + u3*s_A2[(kb+3)*6+j];
        }
        #pragma unroll
        for(int j=0;j<6;j++){ s[j]+=__shfl_xor(s[j],1,64); s[j]+=__shfl_xor(s[j],2,64); }
        if(p<2){
            size_t o = (size_t)(row0+node)*6 + p*3;
            #pragma unroll
            for(int jj=0;jj<3;jj++){
                int j = p*3+jj;
                float t2v = gelu_f(s[j] + s_a2[j]);
                float uu = tanhf(s_dyt[0]*t2v)*s_dyt[1+j] + s_dyt[8+j];
                out_ang[o+jj] = tanhf(uu);
            }
        }
    }
}

// ---------------------------------------------------------------------------
extern "C" void kernel_launch(void* const* d_in, const int* in_sizes, int n_in,
                              void* d_out, int out_size, void* d_ws, size_t ws_size,
                              hipStream_t stream) {
    const float* x      = (const float*)d_in[0];
    const float* coords = (const float*)d_in[1];
    const int*   ei     = (const int*)d_in[2];
    const float* gamma  = (const float*)d_in[4];
    const float* beta   = (const float*)d_in[5];
    const float* W1     = (const float*)d_in[6];
    const float* b1     = (const float*)d_in[7];
    const float* W2     = (const float*)d_in[8];
    const float* b2     = (const float*)d_in[9];
    const float* W3     = (const float*)d_in[10];
    const float* b3     = (const float*)d_in[11];
    const float* embed  = (const float*)d_in[12];
    const float* W_msg  = (const float*)d_in[13];
    const float* b_msg  = (const float*)d_in[14];
    const float* w_coor = (const float*)d_in[15];
    const float* A1     = (const float*)d_in[16];
    const float* a1v    = (const float*)d_in[17];
    const float* A2     = (const float*)d_in[18];
    const float* a2v    = (const float*)d_in[19];
    const float* dalpha = (const float*)d_in[20];
    const float* dw     = (const float*)d_in[21];
    const float* db     = (const float*)d_in[22];

    // ws layout (~44 MB peak):
    //  0      : ids   (128 KB)
    //  128K   : stats (2 KB) + ecnt (2 KB)   <- one 4 KB memset
    //  256K   : weight planes (512 KB) + b1p (1 KB)
    //  1M     : earena u32[512*3072] (6 MB)
    //  10M    : x-hi -> overwritten in-place by h1h -> reused as v bf16
    //  27M    : x-lo -> overwritten in-place by h1l
    char* ws = (char*)d_ws;
    int*      ids   = (int*)ws;
    float*    stats = (float*)(ws + 131072);
    unsigned* ecnt  = (unsigned*)(ws + 131072 + 2048);
    short*    w1th  = (short*)(ws + 262144);
    short*    w1tl  = w1th + 65536;
    short*    w2th  = w1tl + 65536;
    short*    w2tl  = w2th + 32768;
    short*    wmth  = w2tl + 32768;
    short*    wmtl  = wmth + 16384;
    short*    a1th  = wmtl + 16384;
    short*    a1tl  = a1th + 16384;
    float*    b1p   = (float*)(a1tl + 16384);
    unsigned* earena = (unsigned*)(ws + (1<<20));
    unsigned short* h1h = (unsigned short*)(ws + (size_t)10*1048576);
    unsigned short* h1l = (unsigned short*)(ws + (size_t)27*1048576);
    unsigned short* vbf = h1h;   // h1 planes dead after gemm23 -> reuse for v

    float* out_ang = (float*)d_out;
    float* out_z   = out_ang + (size_t)NT*OUTC;
    float* out_co  = out_z   + (size_t)NT*DIMd;

    hipMemsetAsync(stats, 0, 4096, stream);      // stats + ecnt
    prep0_k<<<832, 256, 0, stream>>>(x, stats, W2, W_msg, A1,
        w2th, w2tl, wmth, wmtl, a1th, a1tl, h1h, h1l, ei, ecnt, earena);
    prep1_k<<<65, 256, 0, stream>>>(stats, gamma, beta, W1, b1,
        w1th, w1tl, b1p);
    gemm1_k<<<512, 256, 0, stream>>>(h1h, h1l, w1th, w1tl, b1p);
    gemm23_mfma<<<512, 256, 0, stream>>>(h1h, h1l, w2th, w2tl, b2, W3, b3, ids);
    msgA_k<<<512, 256, 0, stream>>>(ids, ecnt, earena, embed, vbf);
    msgB_k<<<512, 256, 0, stream>>>(vbf, wmth, wmtl, b_msg, w_coor,
        a1th, a1tl, a1v, A2, a2v, dalpha, dw, db, coords,
        out_ang, out_z, out_co);
}

// Round 18
// 252.290 us; speedup vs baseline: 1.4621x; 1.0124x over previous
//
#include <hip/hip_runtime.h>
#include <hip/hip_bf16.h>
#include <math.h>

// Problem constants (match reference)
#define Bg 16
#define Nn 2048
#define Ee (1<<20)
#define NT (Bg*Nn)
#define INC 256
#define DIMd 128
#define OUTC 6
#define ENCH 100
#define NATOMS 20
#define BINCAP 3072   // per-bin edge capacity: mean 2048, sigma~44 -> +23 sigma

typedef __attribute__((ext_vector_type(8))) short bf16x8;
typedef __attribute__((ext_vector_type(4))) float f32x4;

__device__ __forceinline__ float gelu_f(float x){
    return 0.5f*x*(1.0f+erff(x*0.70710678118654752440f));
}
__device__ __forceinline__ unsigned short f2b(float f){
    __hip_bfloat16 h = __float2bfloat16(f);
    return *(unsigned short*)&h;
}
__device__ __forceinline__ float b2f(unsigned short u){
    unsigned v = ((unsigned)u)<<16;
    return __uint_as_float(v);
}
// split fp32 into bf16 hi + bf16 lo (v ~= hi + lo, dropped residual ~2^-18 rel)
__device__ __forceinline__ void splitf(float v, unsigned short& hi, unsigned short& lo){
    unsigned short h = f2b(v);
    hi = h; lo = f2b(v - b2f(h));
}
// async global->LDS, 16B per lane. LDS dest = per-lane ptr matching
// wave-uniform-base + lane*16 layout (m97 pattern).
__device__ __forceinline__ void gld16(const void* g, void* l){
    __builtin_amdgcn_global_load_lds(
        (const __attribute__((address_space(1))) unsigned*)g,
        (__attribute__((address_space(3))) unsigned*)l, 16, 0, 0);
}

// ---- Kernel 1: prep0 ------------------------------------------------------
// TAIL-FIRST block ordering (R11 showed a serial tail: scatter/wsplit blocks
// dispatched last ran at 0.75 blocks/CU after streaming finished -> 45 us).
//  blocks 0..255  : edge bucket-scatter, 4096 edges each
//  blocks 256..319: W2/Wm/A1 weight splits
//  blocks 320..831: BN stats + RAW x hi/lo split, 64 rows/block, float4 loads
__global__ __launch_bounds__(256) void prep0_k(const float* __restrict__ x,
    float* __restrict__ stats, const float* __restrict__ W2,
    const float* __restrict__ Wm, const float* __restrict__ A1,
    short* __restrict__ w2th, short* __restrict__ w2tl,
    short* __restrict__ wmth, short* __restrict__ wmtl,
    short* __restrict__ a1th, short* __restrict__ a1tl,
    unsigned short* __restrict__ xh, unsigned short* __restrict__ xl,
    const int* __restrict__ ei, unsigned* __restrict__ ecnt,
    unsigned* __restrict__ earena)
{
    __shared__ float sp1[4*256], sp2[4*256];     // 8 KB stats partials
    __shared__ unsigned scat[1024];
    int bx = blockIdx.x, tid = threadIdx.x;
    if(bx < 256){
        // ---- edge bucket-scatter (256 blocks; 4096 edges each) ------------
        unsigned* lcnt  = scat;              // 512 u32
        unsigned* gbase = scat + 512;
        for(int l=tid; l<512; l+=256) lcnt[l] = 0;
        __syncthreads();
        int ebase = bx * 4096;
        #pragma unroll 8
        for(int i=0;i<16;i++){
            int e = ebase + i*256 + tid;
            int s = ei[e], d = ei[Ee+e];
            if((s>>11)==(d>>11)) atomicAdd(&lcnt[s>>6], 1u);
        }
        __syncthreads();
        for(int l=tid; l<512; l+=256){
            unsigned c = lcnt[l];
            gbase[l] = c ? atomicAdd(&ecnt[l], c) : 0u;
            lcnt[l] = 0;
        }
        __syncthreads();
        #pragma unroll 8
        for(int i=0;i<16;i++){
            int e = ebase + i*256 + tid;
            int s = ei[e], d = ei[Ee+e];
            if((s>>11)==(d>>11)){
                int bin = s>>6;
                unsigned r = atomicAdd(&lcnt[bin], 1u);
                unsigned pos = gbase[bin] + r;
                if(pos < BINCAP)
                    earena[(size_t)bin*BINCAP + pos] =
                        ((unsigned)(s&63)<<11) | (unsigned)(d&2047);
            }
        }
    } else if(bx < 320){
        int gid = (bx-256)*256 + tid;             // 64 blocks -> 16384 threads
        unsigned short hi, lo;
        for(int l=gid;l<32768;l+=16384){ int n=l>>8,k=l&255;
            splitf(W2[(size_t)k*128+n],hi,lo); w2th[l]=(short)hi; w2tl[l]=(short)lo; }
        for(int l=gid;l<16384;l+=16384){ int n=l>>7,k=l&127;
            splitf(Wm[(size_t)k*128+n],hi,lo); wmth[l]=(short)hi; wmtl[l]=(short)lo; }
        for(int l=gid;l<16384;l+=16384){ int n=l>>7,k=l&127;
            float v=(n<ENCH)? A1[(size_t)k*ENCH+n] : 0.f;
            splitf(v,hi,lo); a1th[l]=(short)hi; a1tl[l]=(short)lo; }
    } else {
        int cg = (tid&63)*4;                     // 4-col group
        int rr = tid>>6;                         // row phase 0..3
        int r0 = (bx-320)*64;
        float s0=0,s1=0,s2=0,s3=0, q0=0,q1=0,q2=0,q3=0;
        #pragma unroll
        for(int i=0;i<16;i++){
            int r = r0 + rr + i*4;
            size_t off = (size_t)r*INC + cg;
            float4 v = *(const float4*)&x[off];
            ushort4 hi, lo;
            splitf(v.x,hi.x,lo.x); splitf(v.y,hi.y,lo.y);
            splitf(v.z,hi.z,lo.z); splitf(v.w,hi.w,lo.w);
            *(ushort4*)&xh[off] = hi;
            *(ushort4*)&xl[off] = lo;
            s0+=v.x; s1+=v.y; s2+=v.z; s3+=v.w;
            q0+=v.x*v.x; q1+=v.y*v.y; q2+=v.z*v.z; q3+=v.w*v.w;
        }
        sp1[rr*256+cg]=s0; sp1[rr*256+cg+1]=s1;
        sp1[rr*256+cg+2]=s2; sp1[rr*256+cg+3]=s3;
        sp2[rr*256+cg]=q0; sp2[rr*256+cg+1]=q1;
        sp2[rr*256+cg+2]=q2; sp2[rr*256+cg+3]=q3;
        __syncthreads();
        {
            float a = sp1[tid]+sp1[256+tid]+sp1[512+tid]+sp1[768+tid];
            float b = sp2[tid]+sp2[256+tid]+sp2[512+tid]+sp2[768+tid];
            atomicAdd(&stats[tid], a);
            atomicAdd(&stats[INC+tid], b);
        }
    }
}

// ---- Kernel 1c: prep1 = BN fold. W1' = s*W1 -> hi/lo planes (blocks 0..63);
//                 b1' = b1 + t@W1 (block 64). Runs after stats complete.
__global__ __launch_bounds__(256) void prep1_k(const float* __restrict__ stats,
    const float* __restrict__ gamma, const float* __restrict__ beta,
    const float* __restrict__ W1, const float* __restrict__ b1,
    short* __restrict__ w1th, short* __restrict__ w1tl, float* __restrict__ b1p)
{
    __shared__ float sc[256], sh[256];
    int bx = blockIdx.x, tid = threadIdx.x;
    {
        float mu  = stats[tid]*(1.0f/NT);
        float var = stats[256+tid]*(1.0f/NT) - mu*mu;
        float s = gamma[tid]/sqrtf(var + 1e-5f);
        sc[tid] = s; sh[tid] = beta[tid] - mu*s;
    }
    __syncthreads();
    if(bx < 64){
        int gid = bx*256 + tid;
        unsigned short hi, lo;
        for(int l=gid;l<65536;l+=16384){ int n=l>>8,k=l&255;
            splitf(sc[k]*W1[(size_t)k*256+n],hi,lo);
            w1th[l]=(short)hi; w1tl[l]=(short)lo; }
    } else {
        float acc = b1[tid];
        for(int k=0;k<256;k++) acc += sh[k]*W1[(size_t)k*256+tid];
        b1p[tid] = acc;
    }
}

// ---- Kernel 2: h1 = gelu(x@W1'+b1'), 64x256 tile, BK=64, 3-term split -----
// BK=64 halves the vmcnt(0) drain count (8->4 barrier pairs). Each 64-k tile
// staged as TWO 32-wide sub-tiles (row stride stays 64 B). LDS 80 KiB ->
// 2 blocks/CU = grid limit, so no occupancy loss. Verified R17.
__global__ __launch_bounds__(256) void gemm1_k(
    unsigned short* xh, unsigned short* xl,
    const short* __restrict__ w1th, const short* __restrict__ w1tl,
    const float* __restrict__ b1p)
{
    __shared__ __align__(16) short sAh[2][64*32], sAl[2][64*32];   // 4 KB each
    __shared__ __align__(16) short sBh[2][256*32], sBl[2][256*32]; // 16 KB each
    int tid = threadIdx.x;
    int row0 = blockIdx.x*64;
    int lane = tid&63, w = tid>>6;
    int ln = lane&15, quad = lane>>4;
    int m0w = (w&1)*32, n0b = (w>>1)*128;
    int ar = tid>>2, kc = (tid&3)*8;             // staging coords
    f32x4 acc[2][8];
    #pragma unroll
    for(int i=0;i<2;i++)
        #pragma unroll
        for(int j=0;j<8;j++) acc[i][j] = (f32x4){0.f,0.f,0.f,0.f};

    for(int k0=0;k0<256;k0+=64){
        #pragma unroll
        for(int h=0;h<2;h++){
            int kb = k0 + 32*h;
            // A: 64 rows x 32 k, 1 issue per plane per half
            gld16(xh + (size_t)(row0+ar)*256 + kb + kc, &sAh[h][tid*8]);
            gld16(xl + (size_t)(row0+ar)*256 + kb + kc, &sAl[h][tid*8]);
            // B: 256 rows x 32 k, 4 issues per plane per half
            #pragma unroll
            for(int i=0;i<4;i++){
                size_t go = (size_t)(i*64+ar)*256 + kb + kc;
                gld16(w1th + go, &sBh[h][i*2048 + tid*8]);
                gld16(w1tl + go, &sBl[h][i*2048 + tid*8]);
            }
        }
        __syncthreads();                 // vmcnt(0) drain -> both halves ready
        #pragma unroll
        for(int h=0;h<2;h++){
            bf16x8 ah[2], al[2];
            #pragma unroll
            for(int tm=0;tm<2;tm++){
                ah[tm] = *(const bf16x8*)&sAh[h][(m0w+tm*16+ln)*32 + quad*8];
                al[tm] = *(const bf16x8*)&sAl[h][(m0w+tm*16+ln)*32 + quad*8];
            }
            #pragma unroll
            for(int tn=0;tn<8;tn++){
                bf16x8 bh = *(const bf16x8*)&sBh[h][(n0b+tn*16+ln)*32 + quad*8];
                bf16x8 bl = *(const bf16x8*)&sBl[h][(n0b+tn*16+ln)*32 + quad*8];
                #pragma unroll
                for(int tm=0;tm<2;tm++){
                    acc[tm][tn] = __builtin_amdgcn_mfma_f32_16x16x32_bf16(al[tm], bh, acc[tm][tn], 0,0,0);
                    acc[tm][tn] = __builtin_amdgcn_mfma_f32_16x16x32_bf16(ah[tm], bl, acc[tm][tn], 0,0,0);
                    acc[tm][tn] = __builtin_amdgcn_mfma_f32_16x16x32_bf16(ah[tm], bh, acc[tm][tn], 0,0,0);
                }
            }
        }
        __syncthreads();                 // LDS reads done before next stage
    }
    #pragma unroll
    for(int tn=0;tn<8;tn++){
        int col = n0b + tn*16 + ln;
        float bias = b1p[col];
        #pragma unroll
        for(int tm=0;tm<2;tm++){
            int rowb = row0 + m0w + tm*16 + quad*4;
            #pragma unroll
            for(int r=0;r<4;r++){
                float hv = gelu_f(acc[tm][tn][r] + bias);
                unsigned short hi, lo;
                splitf(hv, hi, lo);
                xh[(size_t)(rowb+r)*256 + col] = hi;     // h1 overwrites x
                xl[(size_t)(rowb+r)*256 + col] = lo;
            }
        }
    }
}

// ------ Kernel 3: h2=gelu(h1@W2+b2), BK=64 gld16 staging; ------------------
// logits+argmax in-block. R17-verified BK=64 lever applied: drains 8->4.
// Arena union: phase1 staging 48 KB == phase2 h2s+w3s+lgs 48 KB -> 3 blk/CU.
__global__ __launch_bounds__(256) void gemm23_mfma(
    const unsigned short* __restrict__ h1h, const unsigned short* __restrict__ h1l,
    const short* __restrict__ w2th, const short* __restrict__ w2tl,
    const float* __restrict__ b2, const float* __restrict__ W3,
    const float* __restrict__ b3, int* __restrict__ ids)
{
    __shared__ __align__(16) char arena[49152];
    short* sAh = (short*)arena;                 // [2][2048] = 8192 B
    short* sAl = (short*)(arena + 8192);        // [2][2048] = 8192 B
    short* sBh = (short*)(arena + 16384);       // [2][4096] = 16384 B
    short* sBl = (short*)(arena + 32768);       // [2][4096] = 16384 B
    float* h2s = (float*)arena;                 // 64*132 f32 = 33792 B
    float* w3s = (float*)(arena + 33792);       // 2560 f32 = 10240 B
    float* lgs = (float*)(arena + 44032);       // 64*20 f32 = 5120 B
    int tid = threadIdx.x;
    int row0 = blockIdx.x*64;
    int lane = tid&63, w = tid>>6;
    int ln = lane&15, quad = lane>>4;
    int m0w = (w&1)*32, n0w = (w>>1)*64;
    int ar = tid>>2, kc = (tid&3)*8;
    f32x4 acc[2][4];
    #pragma unroll
    for(int i=0;i<2;i++)
        #pragma unroll
        for(int j=0;j<4;j++) acc[i][j] = (f32x4){0.f,0.f,0.f,0.f};

    for(int k0=0;k0<256;k0+=64){
        #pragma unroll
        for(int h=0;h<2;h++){
            int kb = k0 + 32*h;
            gld16(h1h + (size_t)(row0+ar)*256 + kb + kc, &sAh[h*2048 + tid*8]);
            gld16(h1l + (size_t)(row0+ar)*256 + kb + kc, &sAl[h*2048 + tid*8]);
            #pragma unroll
            for(int i=0;i<2;i++){
                size_t go = (size_t)(i*64+ar)*256 + kb + kc;
                gld16(w2th + go, &sBh[h*4096 + i*2048 + tid*8]);
                gld16(w2tl + go, &sBl[h*4096 + i*2048 + tid*8]);
            }
        }
        __syncthreads();                 // vmcnt(0) drain -> both halves ready
        #pragma unroll
        for(int h=0;h<2;h++){
            bf16x8 ah[2], al[2];
            #pragma unroll
            for(int tm=0;tm<2;tm++){
                ah[tm] = *(const bf16x8*)&sAh[h*2048 + (m0w+tm*16+ln)*32 + quad*8];
                al[tm] = *(const bf16x8*)&sAl[h*2048 + (m0w+tm*16+ln)*32 + quad*8];
            }
            #pragma unroll
            for(int tn=0;tn<4;tn++){
                bf16x8 bh = *(const bf16x8*)&sBh[h*4096 + (n0w+tn*16+ln)*32 + quad*8];
                bf16x8 bl = *(const bf16x8*)&sBl[h*4096 + (n0w+tn*16+ln)*32 + quad*8];
                #pragma unroll
                for(int tm=0;tm<2;tm++){
                    acc[tm][tn] = __builtin_amdgcn_mfma_f32_16x16x32_bf16(al[tm], bh, acc[tm][tn], 0,0,0);
                    acc[tm][tn] = __builtin_amdgcn_mfma_f32_16x16x32_bf16(ah[tm], bl, acc[tm][tn], 0,0,0);
                    acc[tm][tn] = __builtin_amdgcn_mfma_f32_16x16x32_bf16(ah[tm], bh, acc[tm][tn], 0,0,0);
                }
            }
        }
        __syncthreads();                 // staging arena dead after last iter
    }
    // epilogue: h2 -> overlaid LDS
    #pragma unroll
    for(int tn=0;tn<4;tn++){
        int col = n0w + tn*16 + ln;
        float bias = b2[col];
        #pragma unroll
        for(int tm=0;tm<2;tm++){
            int rb = m0w + tm*16 + quad*4;
            #pragma unroll
            for(int r=0;r<4;r++)
                h2s[(rb+r)*132 + col] = gelu_f(acc[tm][tn][r] + bias);
        }
    }
    for(int l=tid;l<2560;l+=256) w3s[l] = W3[l];
    __syncthreads();
    int n = tid>>2, q = tid&3;
    float lg[5] = {};
    #pragma unroll 4
    for(int k=0;k<128;k++){
        float h = h2s[n*132+k];
        #pragma unroll
        for(int a=0;a<5;a++) lg[a] += h*w3s[k*20 + q*5 + a];
    }
    #pragma unroll
    for(int a=0;a<5;a++) lgs[n*20 + q*5 + a] = lg[a] + b3[q*5+a];
    __syncthreads();
    if(tid<64){                                     // numpy argmax: first max wins
        float best = lgs[tid*20]; int bi = 0;
        #pragma unroll
        for(int a=1;a<20;a++){ float v2 = lgs[tid*20+a]; if(v2>best){best=v2;bi=a;} }
        ids[row0+tid] = bi;
    }
}

// ---- Kernel 4a: aggregation only -> v bf16 to workspace --------------------
// grid 512 bins x 256. LDS 33.8 KiB -> 4 blocks/CU. 3 barriers total.
__global__ __launch_bounds__(256) void msgA_k(
    const int* __restrict__ ids, const unsigned* __restrict__ ecnt,
    const unsigned* __restrict__ earena, const float* __restrict__ embed,
    unsigned short* __restrict__ vbf)
{
    __shared__ unsigned lmask[64*64];          // 16 KiB dst bitmask per node
    __shared__ unsigned ind[NATOMS*64];        // 5 KiB indicator bitmasks
    __shared__ unsigned char sid[2048];        // atom id per graph node
    __shared__ float emb[NATOMS*128];          // 10 KiB embedding table
    int tid = threadIdx.x;
    int bin = blockIdx.x;
    int row0 = bin*64;
    int g = bin>>5, tile = bin&31;
    int lane = tid&63, w = tid>>6;

    // --- phase 0 ------------------------------------------------------------
    for(int l=tid;l<NATOMS*128;l+=256) emb[l] = embed[l];
    #pragma unroll
    for(int i=0;i<8;i++){ int j = tid + i*256; sid[j] = (unsigned char)ids[g*Nn + j]; }
    #pragma unroll
    for(int i=0;i<16;i++) lmask[tid + i*256] = 0;
    int nb = min((int)ecnt[bin], BINCAP);
    __syncthreads();

    // --- phase 1: ballot indicator bitmasks + LDS adjacency build -----------
    for(int wp=w; wp<32; wp+=4){
        int a = sid[wp*64 + lane];
        #pragma unroll
        for(int atom=0; atom<NATOMS; atom++){
            unsigned long long bm = __ballot(a==atom);
            if(lane<2) ind[atom*64 + wp*2 + lane] = (unsigned)(bm >> (32*lane));
        }
    }
    for(int i=tid; i<nb; i+=256){
        unsigned wv = earena[(size_t)bin*BINCAP + i];
        int sl = wv>>11, dl = wv & 2047;
        atomicOr(&lmask[sl*64 + (dl>>5)], 1u<<(dl&31));
    }
    __syncthreads();

    // --- phase 2: per-node counts popcount(lmask & ind), 4-lane split -------
    int node = tid>>2, p = tid&3;
    unsigned mw[16];
    {
        const unsigned* mrow = &lmask[node*64 + p*16];
        *(uint4*)&mw[0]  = *(const uint4*)&mrow[0];
        *(uint4*)&mw[4]  = *(const uint4*)&mrow[4];
        *(uint4*)&mw[8]  = *(const uint4*)&mrow[8];
        *(uint4*)&mw[12] = *(const uint4*)&mrow[12];
    }
    int degi = 0;
    #pragma unroll
    for(int w2=0;w2<16;w2++) degi += __popc(mw[w2]);
    float cnt[NATOMS];
    #pragma unroll
    for(int a=0;a<NATOMS;a++){
        int c = 0;
        const unsigned* ia = &ind[a*64 + p*16];
        #pragma unroll
        for(int w2=0;w2<16;w2++) c += __popc(mw[w2] & ia[w2]);
        cnt[a] = (float)c;
    }
    #pragma unroll
    for(int a=0;a<NATOMS;a++){
        cnt[a] += __shfl_xor(cnt[a],1,64);
        cnt[a] += __shfl_xor(cnt[a],2,64);
    }
    float deg = (float)degi;
    deg += __shfl_xor(deg,1,64);
    deg += __shfl_xor(deg,2,64);

    // --- v = emb[own] + (sum_a cnt_a emb_a)/max(deg,1) -> global bf16 -------
    {
        float inv = 1.0f / fmaxf(deg, 1.0f);
        int oid = sid[tile*64 + node];
        int d0 = p*32;
        float vv[32];
        #pragma unroll
        for(int d=0;d<32;d++) vv[d]=0.f;
        #pragma unroll
        for(int a=0;a<NATOMS;a++){
            float ca = cnt[a];
            const float* ea = &emb[a*128 + d0];
            #pragma unroll
            for(int d=0;d<32;d+=4){
                float4 e = *(const float4*)&ea[d];
                vv[d]+=ca*e.x; vv[d+1]+=ca*e.y; vv[d+2]+=ca*e.z; vv[d+3]+=ca*e.w;
            }
        }
        const float* eo = &emb[oid*128 + d0];
        unsigned short* dst = vbf + (size_t)(row0+node)*128 + d0;
        #pragma unroll
        for(int d=0;d<32;d+=4){
            float4 e = *(const float4*)&eo[d];
            ushort4 o;
            o.x = f2b(e.x + vv[d]*inv);
            o.y = f2b(e.y + vv[d+1]*inv);
            o.z = f2b(e.z + vv[d+2]*inv);
            o.w = f2b(e.w + vv[d+3]*inv);
            *(ushort4*)&dst[d] = o;
        }
    }
}

// ---- Kernel 4b: hout GEMM + heads, gld16-staged MFMA operands --------------
// hout GEMM stages A (v, 64x32) + B (Wm hi/lo, 128x32 each); t1 GEMM stages
// B (A1 hi/lo) only (A = houts already in LDS). LDS ~42.9 KiB -> 3 blocks/CU.
__global__ __launch_bounds__(256) void msgB_k(
    const unsigned short* __restrict__ vbf,
    const short* __restrict__ wmth, const short* __restrict__ wmtl,
    const float* __restrict__ b_msg, const float* __restrict__ w_coor,
    const short* __restrict__ a1th, const short* __restrict__ a1tl,
    const float* __restrict__ a1v, const float* __restrict__ A2,
    const float* __restrict__ a2v, const float* __restrict__ dalpha,
    const float* __restrict__ dw, const float* __restrict__ db,
    const float* __restrict__ coords, float* __restrict__ out_ang,
    float* __restrict__ out_z, float* __restrict__ out_co)
{
    __shared__ __align__(16) short sA[64*32];              // 4 KB A staging
    __shared__ __align__(16) short sBh[128*32], sBl[128*32]; // 8 KB each
    __shared__ unsigned short houts[64*136];   // hout bf16; later t1s [64][104]
    __shared__ float s_bm[128], s_wc[384], s_A2[624], s_a1[104];
    __shared__ float s_dyt[16], s_a2[8];
    int tid = threadIdx.x;
    int row0 = blockIdx.x*64;
    int lane = tid&63, w = tid>>6;
    int ln = lane&15, quad = lane>>4;
    int m0w = (w&1)*32, n0w = (w>>1)*64;
    int ar = tid>>2, kc = (tid&3)*8;           // staging coords

    // constants -> LDS (consumed only after the first in-loop barrier)
    if(tid<128) s_bm[tid] = b_msg[tid];
    if(tid<104) s_a1[tid] = (tid<ENCH) ? a1v[tid] : 0.f;
    for(int l=tid;l<384;l+=256) s_wc[l] = w_coor[l];
    for(int l=tid;l<624;l+=256) s_A2[l] = (l<600) ? A2[l] : 0.f;
    if(tid==0)  s_dyt[0] = dalpha[0];
    if(tid<6){ s_dyt[1+tid] = dw[tid]; s_dyt[8+tid] = db[tid]; }
    if(tid<8)  s_a2[tid] = (tid<6) ? a2v[tid] : 0.f;

    // ---- hout = gelu(v @ W_msg + b), 2-term W split, gld16 staging ---------
    f32x4 acc[2][4];
    #pragma unroll
    for(int i=0;i<2;i++)
        #pragma unroll
        for(int j=0;j<4;j++) acc[i][j] = (f32x4){0.f,0.f,0.f,0.f};
    for(int k0=0;k0<128;k0+=32){
        gld16(vbf + (size_t)(row0+ar)*128 + k0 + kc, &sA[tid*8]);
        #pragma unroll
        for(int i=0;i<2;i++){
            size_t go = (size_t)(i*64+ar)*128 + k0 + kc;
            gld16(wmth + go, &sBh[i*2048 + tid*8]);
            gld16(wmtl + go, &sBl[i*2048 + tid*8]);
        }
        __syncthreads();                 // vmcnt(0) drain -> tiles ready
        bf16x8 av[2];
        #pragma unroll
        for(int tm=0;tm<2;tm++)
            av[tm] = *(const bf16x8*)&sA[(m0w+tm*16+ln)*32 + quad*8];
        #pragma unroll
        for(int tn=0;tn<4;tn++){
            bf16x8 bh = *(const bf16x8*)&sBh[(n0w+tn*16+ln)*32 + quad*8];
            bf16x8 bl = *(const bf16x8*)&sBl[(n0w+tn*16+ln)*32 + quad*8];
            #pragma unroll
            for(int tm=0;tm<2;tm++){
                acc[tm][tn] = __builtin_amdgcn_mfma_f32_16x16x32_bf16(av[tm], bl, acc[tm][tn], 0,0,0);
                acc[tm][tn] = __builtin_amdgcn_mfma_f32_16x16x32_bf16(av[tm], bh, acc[tm][tn], 0,0,0);
            }
        }
        __syncthreads();                 // LDS reads done before next stage
    }
    // epilogue: z fp32 + hout bf16 to LDS
    #pragma unroll
    for(int tn=0;tn<4;tn++){
        int col = n0w + tn*16 + ln;
        float bias = s_bm[col];
        #pragma unroll
        for(int tm=0;tm<2;tm++){
            int mb2 = m0w + tm*16 + quad*4;
            #pragma unroll
            for(int r=0;r<4;r++){
                float hv = gelu_f(acc[tm][tn][r] + bias);
                out_z[(size_t)(row0+mb2+r)*128 + col] = hv;
                houts[(mb2+r)*136 + col] = f2b(hv);
            }
        }
    }
    __syncthreads();                    // houts ready

    int node = tid>>2, p = tid&3;
    // ---- coors: 4-lane k-split dot with w_coor -----------------------------
    {
        float d0=0.f, d1=0.f, d2=0.f;
        int kb = p*32;
        #pragma unroll
        for(int k=0;k<32;k+=4){
            ushort4 hv = *(const ushort4*)&houts[node*136 + kb + k];
            float h0=b2f(hv.x),h1=b2f(hv.y),h2=b2f(hv.z),h3=b2f(hv.w);
            const float* wc = &s_wc[(kb+k)*3];
            d0 += h0*wc[0]+h1*wc[3]+h2*wc[6]+h3*wc[9];
            d1 += h0*wc[1]+h1*wc[4]+h2*wc[7]+h3*wc[10];
            d2 += h0*wc[2]+h1*wc[5]+h2*wc[8]+h3*wc[11];
        }
        d0 += __shfl_xor(d0,1,64); d0 += __shfl_xor(d0,2,64);
        d1 += __shfl_xor(d1,1,64); d1 += __shfl_xor(d1,2,64);
        d2 += __shfl_xor(d2,1,64); d2 += __shfl_xor(d2,2,64);
        if(p==0){
            size_t o = (size_t)(row0+node)*3;
            out_co[o+0] = coords[o+0] + tanhf(d0);
            out_co[o+1] = coords[o+1] + tanhf(d1);
            out_co[o+2] = coords[o+2] + tanhf(d2);
        }
    }

    // ---- t1 = gelu(hout @ A1 + a1), 2-term split, gld16-staged B -----------
    f32x4 acc2[2][4];
    #pragma unroll
    for(int i=0;i<2;i++)
        #pragma unroll
        for(int j=0;j<4;j++) acc2[i][j] = (f32x4){0.f,0.f,0.f,0.f};
    for(int k0=0;k0<128;k0+=32){
        #pragma unroll
        for(int i=0;i<2;i++){
            size_t go = (size_t)(i*64+ar)*128 + k0 + kc;
            gld16(a1th + go, &sBh[i*2048 + tid*8]);
            gld16(a1tl + go, &sBl[i*2048 + tid*8]);
        }
        __syncthreads();
        bf16x8 ah[2];
        #pragma unroll
        for(int tm=0;tm<2;tm++)
            ah[tm] = *(const bf16x8*)&houts[(m0w+tm*16+ln)*136 + k0 + quad*8];
        #pragma unroll
        for(int tn=0;tn<4;tn++){
            bf16x8 bh = *(const bf16x8*)&sBh[(n0w+tn*16+ln)*32 + quad*8];
            bf16x8 bl = *(const bf16x8*)&sBl[(n0w+tn*16+ln)*32 + quad*8];
            #pragma unroll
            for(int tm=0;tm<2;tm++){
                acc2[tm][tn] = __builtin_amdgcn_mfma_f32_16x16x32_bf16(ah[tm], bl, acc2[tm][tn], 0,0,0);
                acc2[tm][tn] = __builtin_amdgcn_mfma_f32_16x16x32_bf16(ah[tm], bh, acc2[tm][tn], 0,0,0);
            }
        }
        __syncthreads();
    }
    unsigned short* t1s = houts;        // [64][104] (houts reads done)
    #pragma unroll
    for(int tn=0;tn<4;tn++){
        int col = n0w + tn*16 + ln;
        if(col < 104){
            float bias = s_a1[col];
            #pragma unroll
            for(int tm=0;tm<2;tm++){
                int mb2 = m0w + tm*16 + quad*4;
                #pragma unroll
                for(int r=0;r<4;r++)
                    t1s[(mb2+r)*104 + col] = f2b(gelu_f(acc2[tm][tn][r] + bias));
            }
        }
    }
    __syncthreads();

    // ---- t2 = gelu(t1@A2+a2); DyT; angles ----------------------------------
    {
        int g0 = (p<2) ? p*7 : 14+(p-2)*6;
        int gcount = (p<2) ? 7 : 6;
        float s[6] = {0.f,0.f,0.f,0.f,0.f,0.f};
        for(int gg=0; gg<gcount; gg++){
            int kb = (g0+gg)*4;
            ushort4 tv = *(const ushort4*)&t1s[node*104 + kb];
            float u0=b2f(tv.x), u1=b2f(tv.y), u2=b2f(tv.z), u3=b2f(tv.w);
            #pragma unroll
            for(int j=0;j<6;j++)
                s[j] += u0*s_A2[kb*6+j] + u1*s_A2[(kb+1)*6+j]
                      + u2*s_A2[(kb+2)*6+j] + u3*s_A2[(kb+3)*6+j];
        }
        #pragma unroll
        for(int j=0;j<6;j++){ s[j]+=__shfl_xor(s[j],1,64); s[j]+=__shfl_xor(s[j],2,64); }
        if(p<2){
            size_t o = (size_t)(row0+node)*6 + p*3;
            #pragma unroll
            for(int jj=0;jj<3;jj++){
                int j = p*3+jj;
                float t2v = gelu_f(s[j] + s_a2[j]);
                float uu = tanhf(s_dyt[0]*t2v)*s_dyt[1+j] + s_dyt[8+j];
                out_ang[o+jj] = tanhf(uu);
            }
        }
    }
}

// ---------------------------------------------------------------------------
extern "C" void kernel_launch(void* const* d_in, const int* in_sizes, int n_in,
                              void* d_out, int out_size, void* d_ws, size_t ws_size,
                              hipStream_t stream) {
    const float* x      = (const float*)d_in[0];
    const float* coords = (const float*)d_in[1];
    const int*   ei     = (const int*)d_in[2];
    const float* gamma  = (const float*)d_in[4];
    const float* beta   = (const float*)d_in[5];
    const float* W1     = (const float*)d_in[6];
    const float* b1     = (const float*)d_in[7];
    const float* W2     = (const float*)d_in[8];
    const float* b2     = (const float*)d_in[9];
    const float* W3     = (const float*)d_in[10];
    const float* b3     = (const float*)d_in[11];
    const float* embed  = (const float*)d_in[12];
    const float* W_msg  = (const float*)d_in[13];
    const float* b_msg  = (const float*)d_in[14];
    const float* w_coor = (const float*)d_in[15];
    const float* A1     = (const float*)d_in[16];
    const float* a1v    = (const float*)d_in[17];
    const float* A2     = (const float*)d_in[18];
    const float* a2v    = (const float*)d_in[19];
    const float* dalpha = (const float*)d_in[20];
    const float* dw     = (const float*)d_in[21];
    const float* db     = (const float*)d_in[22];

    // ws layout (~44 MB peak):
    //  0      : ids   (128 KB)
    //  128K   : stats (2 KB) + ecnt (2 KB)   <- one 4 KB memset
    //  256K   : weight planes (512 KB) + b1p (1 KB)
    //  1M     : earena u32[512*3072] (6 MB)
    //  10M    : x-hi -> overwritten in-place by h1h -> reused as v bf16
    //  27M    : x-lo -> overwritten in-place by h1l
    char* ws = (char*)d_ws;
    int*      ids   = (int*)ws;
    float*    stats = (float*)(ws + 131072);
    unsigned* ecnt  = (unsigned*)(ws + 131072 + 2048);
    short*    w1th  = (short*)(ws + 262144);
    short*    w1tl  = w1th + 65536;
    short*    w2th  = w1tl + 65536;
    short*    w2tl  = w2th + 32768;
    short*    wmth  = w2tl + 32768;
    short*    wmtl  = wmth + 16384;
    short*    a1th  = wmtl + 16384;
    short*    a1tl  = a1th + 16384;
    float*    b1p   = (float*)(a1tl + 16384);
    unsigned* earena = (unsigned*)(ws + (1<<20));
    unsigned short* h1h = (unsigned short*)(ws + (size_t)10*1048576);
    unsigned short* h1l = (unsigned short*)(ws + (size_t)27*1048576);
    unsigned short* vbf = h1h;   // h1 planes dead after gemm23 -> reuse for v

    float* out_ang = (float*)d_out;
    float* out_z   = out_ang + (size_t)NT*OUTC;
    float* out_co  = out_z   + (size_t)NT*DIMd;

    hipMemsetAsync(stats, 0, 4096, stream);      // stats + ecnt
    prep0_k<<<832, 256, 0, stream>>>(x, stats, W2, W_msg, A1,
        w2th, w2tl, wmth, wmtl, a1th, a1tl, h1h, h1l, ei, ecnt, earena);
    prep1_k<<<65, 256, 0, stream>>>(stats, gamma, beta, W1, b1,
        w1th, w1tl, b1p);
    gemm1_k<<<512, 256, 0, stream>>>(h1h, h1l, w1th, w1tl, b1p);
    gemm23_mfma<<<512, 256, 0, stream>>>(h1h, h1l, w2th, w2tl, b2, W3, b3, ids);
    msgA_k<<<512, 256, 0, stream>>>(ids, ecnt, earena, embed, vbf);
    msgB_k<<<512, 256, 0, stream>>>(vbf, wmth, wmtl, b_msg, w_coor,
        a1th, a1tl, a1v, A2, a2v, dalpha, dw, db, coords,
        out_ang, out_z, out_co);
}